// Round 7
// baseline (220.001 us; speedup 1.0000x reference)
//
#include <hip/hip_runtime.h>
#include <math.h>

#define BB   2
#define NN   2048
#define DDIM 512
#define HH   8
#define DH   64
#define MTOT (BB*NN)      // 4096
#define LDK  72           // ushort stride (v_transpose scratch only)
#define EE   (BB*HH*NN*DH)   // 2,097,152 elems per Q/K/V-like array
#define WN   (DDIM*DDIM)     // 262,144 elems per weight
#define NSLOT (BB*HH*32*4)   // 2048 partial slots (bh x qt x <=4 chunks)

typedef __attribute__((ext_vector_type(8))) short bf16x8;   // 8 bf16 = 4 VGPRs
typedef __attribute__((ext_vector_type(4))) float f32x4;

__device__ __forceinline__ float softplus_f(float x) {
    return x > 20.f ? x : log1pf(expf(x));
}
__device__ __forceinline__ unsigned short f2bf(float x) {   // round-to-nearest-even
    union { float f; unsigned u; } v; v.f = x;
    unsigned r = v.u + 0x7fffu + ((v.u >> 16) & 1u);
    return (unsigned short)(r >> 16);
}
__device__ __forceinline__ float bf2f(unsigned short h) {
    union { unsigned u; float f; } v; v.u = ((unsigned)h) << 16; return v.f;
}

// ---------------------------------------------------------------------------
// Split fp32 -> bf16 hi/lo pairs. blockIdx.y selects {x, Wq, Wk, Wv, Wo}.
// ---------------------------------------------------------------------------
__global__ __launch_bounds__(256)
void split_hl(const float* __restrict__ x,  const float* __restrict__ Wq,
              const float* __restrict__ Wk, const float* __restrict__ Wv,
              const float* __restrict__ Wo,
              unsigned short* __restrict__ xh,  unsigned short* __restrict__ xl,
              unsigned short* __restrict__ wqh, unsigned short* __restrict__ wql,
              unsigned short* __restrict__ wkh, unsigned short* __restrict__ wkl,
              unsigned short* __restrict__ wvh, unsigned short* __restrict__ wvl,
              unsigned short* __restrict__ woh, unsigned short* __restrict__ wol)
{
    const float* src; unsigned short *dh, *dl; int nq;
    switch (blockIdx.y) {
        case 0:  src = x;  dh = xh;  dl = xl;  nq = EE / 4; break;
        case 1:  src = Wq; dh = wqh; dl = wql; nq = WN / 4; break;
        case 2:  src = Wk; dh = wkh; dl = wkl; nq = WN / 4; break;
        case 3:  src = Wv; dh = wvh; dl = wvl; nq = WN / 4; break;
        default: src = Wo; dh = woh; dl = wol; nq = WN / 4; break;
    }
    for (int i = blockIdx.x * 256 + threadIdx.x; i < nq; i += gridDim.x * 256) {
        float4 v = *(const float4*)(src + 4 * (size_t)i);
        ushort4 h, l;
        h.x = f2bf(v.x); l.x = f2bf(v.x - bf2f(h.x));
        h.y = f2bf(v.y); l.y = f2bf(v.y - bf2f(h.y));
        h.z = f2bf(v.z); l.z = f2bf(v.z - bf2f(h.z));
        h.w = f2bf(v.w); l.w = f2bf(v.w - bf2f(h.w));
        *(ushort4*)(dh + 4 * (size_t)i) = h;
        *(ushort4*)(dl + 4 * (size_t)i) = l;
    }
}

// ---------------------------------------------------------------------------
// Unified hi/lo-compensated bf16 MFMA GEMM, 64x128 tile (3 blocks/CU for the
// proj launch vs 1.5 at 128x128 -- the rounds-5/6 version was latency-bound).
// BK=32, waves 2m x 2n, each wave 32x64 = 2x4 tiles x 3 MFMAs = 24/iter.
// LDS [kq][rows][8] ushort: fragment reads are lane-contiguous (conflict-free).
// ---------------------------------------------------------------------------
__global__ __launch_bounds__(256, 3)
void mm_mfma(const unsigned short* __restrict__ Ahg, const unsigned short* __restrict__ Alg,
             const unsigned short* __restrict__ W0h, const unsigned short* __restrict__ W0l,
             const unsigned short* __restrict__ W1h, const unsigned short* __restrict__ W1l,
             const unsigned short* __restrict__ W2h, const unsigned short* __restrict__ W2l,
             const int is_out,
             unsigned short* __restrict__ Qhi, unsigned short* __restrict__ Qlo,
             unsigned short* __restrict__ Khi, unsigned short* __restrict__ Klo,
             unsigned short* __restrict__ Vb, float* __restrict__ Outp,
             float* __restrict__ QN, float* __restrict__ KN)
{
    const int mode = is_out ? 3 : (int)blockIdx.z;
    const unsigned short* Wh = (mode == 1) ? W1h : ((mode == 2) ? W2h : W0h);
    const unsigned short* Wl = (mode == 1) ? W1l : ((mode == 2) ? W2l : W0l);
    const int m0 = blockIdx.x * 64, n0 = blockIdx.y * 128;

    __shared__ unsigned short Ah_s[4 * 64 * 8];    // [kq][64][8]
    __shared__ unsigned short Al_s[4 * 64 * 8];
    __shared__ unsigned short Bh_s[4 * 128 * 8];   // [kq][128][8]
    __shared__ unsigned short Bl_s[4 * 128 * 8];

    const int tid  = threadIdx.x;
    const int lane = tid & 63, lx = lane & 15, q4 = lane >> 4;
    const int w = tid >> 6, wm = w & 1, wn = w >> 1;
    const int rowA = tid & 63,  kqA = tid >> 6;    // A staging: 1 uint4/thread/array
    const int rowB = tid & 127, kb  = tid >> 7;    // B staging: 2 uint4/thread/array

    f32x4 acc[2][4];
    #pragma unroll
    for (int mt = 0; mt < 2; ++mt)
        #pragma unroll
        for (int nt = 0; nt < 4; ++nt)
            acc[mt][nt] = (f32x4){0.f, 0.f, 0.f, 0.f};

    const int am = m0 + rowA;
    const int ab = am >> 11, an = am & 2047;
    const size_t brow = (size_t)(n0 + rowB) * DDIM;

    // preload k0 = 0
    uint4 rah, ral, rbh0, rbh1, rbl0, rbl1;
    {
        const int e = kqA * 8;
        size_t aoff = (mode == 3)
            ? ((((size_t)(ab * HH + (e >> 6)) * NN + an) << 6) + (e & 63))
            : ((size_t)am * DDIM + e);
        rah = *(const uint4*)(Ahg + aoff);
        ral = *(const uint4*)(Alg + aoff);
        const int eb = kb * 8;
        rbh0 = *(const uint4*)(Wh + brow + eb);
        rbh1 = *(const uint4*)(Wh + brow + eb + 16);
        rbl0 = *(const uint4*)(Wl + brow + eb);
        rbl1 = *(const uint4*)(Wl + brow + eb + 16);
    }

    for (int k0 = 0; k0 < DDIM; k0 += 32) {
        __syncthreads();    // previous compute done
        *(uint4*)&Ah_s[(kqA << 9) + (rowA << 3)] = rah;
        *(uint4*)&Al_s[(kqA << 9) + (rowA << 3)] = ral;
        *(uint4*)&Bh_s[(kb << 10) + (rowB << 3)]       = rbh0;
        *(uint4*)&Bh_s[((kb + 2) << 10) + (rowB << 3)] = rbh1;
        *(uint4*)&Bl_s[(kb << 10) + (rowB << 3)]       = rbl0;
        *(uint4*)&Bl_s[((kb + 2) << 10) + (rowB << 3)] = rbl1;
        __syncthreads();    // staged tile visible

        if (k0 + 32 < DDIM) {   // prefetch next K-slice (overlaps MFMAs)
            const int e = k0 + 32 + kqA * 8;
            size_t aoff = (mode == 3)
                ? ((((size_t)(ab * HH + (e >> 6)) * NN + an) << 6) + (e & 63))
                : ((size_t)am * DDIM + e);
            rah = *(const uint4*)(Ahg + aoff);
            ral = *(const uint4*)(Alg + aoff);
            const int eb = k0 + 32 + kb * 8;
            rbh0 = *(const uint4*)(Wh + brow + eb);
            rbh1 = *(const uint4*)(Wh + brow + eb + 16);
            rbl0 = *(const uint4*)(Wl + brow + eb);
            rbl1 = *(const uint4*)(Wl + brow + eb + 16);
        }

        bf16x8 fah[2], fal[2], fbh[4], fbl[4];
        #pragma unroll
        for (int mt = 0; mt < 2; ++mt) {
            const int off = (q4 << 9) + ((wm * 32 + mt * 16 + lx) << 3);
            fah[mt] = *(const bf16x8*)&Ah_s[off];
            fal[mt] = *(const bf16x8*)&Al_s[off];
        }
        #pragma unroll
        for (int nt = 0; nt < 4; ++nt) {
            const int off = (q4 << 10) + ((wn * 64 + nt * 16 + lx) << 3);
            fbh[nt] = *(const bf16x8*)&Bh_s[off];
            fbl[nt] = *(const bf16x8*)&Bl_s[off];
        }
        #pragma unroll
        for (int mt = 0; mt < 2; ++mt)
            #pragma unroll
            for (int nt = 0; nt < 4; ++nt) {
                acc[mt][nt] = __builtin_amdgcn_mfma_f32_16x16x32_bf16(fah[mt], fbh[nt], acc[mt][nt], 0, 0, 0);
                acc[mt][nt] = __builtin_amdgcn_mfma_f32_16x16x32_bf16(fah[mt], fbl[nt], acc[mt][nt], 0, 0, 0);
                acc[mt][nt] = __builtin_amdgcn_mfma_f32_16x16x32_bf16(fal[mt], fbh[nt], acc[mt][nt], 0, 0, 0);
            }
    }

    // ---- fused row norms (modes 0/1): this wave's wn-half is one head ----
    if (mode == 0 || mode == 1) {
        float* Np = (mode == 0) ? QN : KN;
        const int head = (n0 + wn * 64) >> 6;
        #pragma unroll
        for (int mt = 0; mt < 2; ++mt)
            #pragma unroll
            for (int r = 0; r < 4; ++r) {
                float s = 0.f;
                #pragma unroll
                for (int nt = 0; nt < 4; ++nt) s = fmaf(acc[mt][nt][r], acc[mt][nt][r], s);
                s += __shfl_xor(s, 1);
                s += __shfl_xor(s, 2);
                s += __shfl_xor(s, 4);
                s += __shfl_xor(s, 8);
                if (lx == 0) {
                    const int m = m0 + wm * 32 + mt * 16 + q4 * 4 + r;
                    Np[(size_t)((m >> 11) * HH + head) * NN + (m & 2047)] = s;
                }
            }
    }

    // epilogue: C row m = q4*4+reg, col j = lx (verified mapping)
    #pragma unroll
    for (int mt = 0; mt < 2; ++mt) {
        #pragma unroll
        for (int r = 0; r < 4; ++r) {
            const int m = m0 + wm * 32 + mt * 16 + q4 * 4 + r;
            const int b = m >> 11, n2 = m & 2047;
            #pragma unroll
            for (int nt = 0; nt < 4; ++nt) {
                const int j = n0 + wn * 64 + nt * 16 + lx;
                const float v = acc[mt][nt][r];
                if (mode == 3) {
                    Outp[(size_t)m * DDIM + j] = v;
                } else {
                    const size_t idx = (((size_t)(b * HH + (j >> 6)) * NN + n2) << 6) + (j & 63);
                    if (mode == 2) {
                        Vb[idx] = f2bf(v);
                    } else {
                        const unsigned short h = f2bf(v);
                        const unsigned short l = f2bf(v - bf2f(h));
                        if (mode == 0) { Qhi[idx] = h; Qlo[idx] = l; }
                        else           { Khi[idx] = h; Klo[idx] = l; }
                    }
                }
            }
        }
    }
}

// ---------------------------------------------------------------------------
// V transpose: Vb [B,H,N,64] bf16 -> Vt [B,H,64,N] bf16
// ---------------------------------------------------------------------------
__global__ __launch_bounds__(256)
void v_transpose(const unsigned short* __restrict__ Vb, unsigned short* __restrict__ Vt)
{
    __shared__ unsigned short T[64 * LDK];
    const int id = blockIdx.x;          // 512 = 16 bh * 32 n-tiles
    const int bh = id >> 5, nt = id & 31;
    const size_t ibase = (((size_t)bh * NN + nt * 64) << 6);
    const int row = threadIdx.x >> 2, ch = threadIdx.x & 3;

    #pragma unroll
    for (int half = 0; half < 2; ++half) {
        const int col = ch * 8 + half * 32;
        *(uint4*)&T[row * LDK + col] = *(const uint4*)(Vb + ibase + (row << 6) + col);
    }
    __syncthreads();

    const size_t obase = (size_t)bh * 64 * NN;
    #pragma unroll
    for (int half = 0; half < 2; ++half) {
        const int col = ch * 8 + half * 32;
        union { unsigned short u[8]; uint4 v; } tmp;
        #pragma unroll
        for (int j = 0; j < 8; ++j) tmp.u[j] = T[(col + j) * LDK + row];
        *(uint4*)(Vt + obase + (size_t)row * NN + nt * 64 + col) = tmp.v;
    }
}

// ---------------------------------------------------------------------------
// MFMA flash attention, split-K over balanced chunks. Round-7:
//  - LDS [chunk][key|d|row][8] layouts -> lane-contiguous, conflict-free
//    fragment reads (round-6 pad-72 layout was ~8-way conflicted).
//  - l computed via MFMA against all-ones B fragment (no shuffle-sum chain).
//  - scores in log2 domain (exp2f), combine updated to match.
//  - chunk kt-ranges balanced within each qt: lengths differ by <=1.
// ---------------------------------------------------------------------------
__global__ __launch_bounds__(256, 4)
void attn_mfma(const unsigned short* __restrict__ Qhi, const unsigned short* __restrict__ Qlo,
               const unsigned short* __restrict__ Khi, const unsigned short* __restrict__ Klo,
               const unsigned short* __restrict__ Vt,
               const float* __restrict__ QN, const float* __restrict__ KN,
               const float* __restrict__ pLC, const float* __restrict__ pLB,
               float* __restrict__ Opart, float* __restrict__ Mp, float* __restrict__ Lp)
{
    __shared__ unsigned short Kh_s[8 * 64 * 8];   // [dq][key][8]
    __shared__ unsigned short Kl_s[8 * 64 * 8];
    __shared__ unsigned short Vt_s[8 * 64 * 8];   // [keyq][d][8]
    __shared__ unsigned short P_s [8 * 64 * 8];   // [keyq][row][8]
    __shared__ float kn_s[64];
    __shared__ float qn_s[64];

    // decode (qt, chunk): group g = qt>>3 has C=g+1 chunks; base(g)=4g(g+1)
    const int idx = blockIdx.x;
    const int g   = (idx >= 48) ? 3 : (idx >= 24) ? 2 : (idx >= 8) ? 1 : 0;
    const int rem = idx - 4 * g * (g + 1);
    const int C   = g + 1;
    const int qt  = g * 8 + rem / C;
    const int c0  = rem % C;
    const int bh  = blockIdx.y;
    const int nk  = qt + 1;
    const int kt0  = (c0 * nk) / C;        // balanced ranges (len diff <= 1)
    const int kend = ((c0 + 1) * nk) / C;

    const int tid  = threadIdx.x;
    const int w    = tid >> 6;
    const int lane = tid & 63;
    const int lx   = lane & 15;
    const int q4   = lane >> 4;

    const float hc    = softplus_f(pLC[0]);
    const float betaL = (softplus_f(pLB[0]) + 0.5f) * 1.44269504f;  // log2 domain

    const size_t base = ((size_t)bh * NN) << 6;

    // all-ones bf16 fragment for l-via-MFMA
    union { unsigned short u[8]; bf16x8 v; } ones_u;
    #pragma unroll
    for (int j = 0; j < 8; ++j) ones_u.u[j] = 0x3F80;
    const bf16x8 ones = ones_u.v;

    // Q fragments (A-layout: m=lx, k=q4*8+j), registers for whole block
    const unsigned short* qrh = Qhi + base + ((size_t)(qt * 64 + w * 16 + lx) << 6) + q4 * 8;
    const unsigned short* qrl = Qlo + base + ((size_t)(qt * 64 + w * 16 + lx) << 6) + q4 * 8;
    const bf16x8 qh0 = *(const bf16x8*)(qrh);
    const bf16x8 qh1 = *(const bf16x8*)(qrh + 32);
    const bf16x8 ql0 = *(const bf16x8*)(qrl);
    const bf16x8 ql1 = *(const bf16x8*)(qrl + 32);

    if (tid < 64) qn_s[tid] = QN[(size_t)bh * NN + qt * 64 + tid];

    f32x4 Oacc[4];
    f32x4 Lacc = (f32x4){0.f, 0.f, 0.f, 0.f};
    float m_st[4];
    #pragma unroll
    for (int r = 0; r < 4; ++r) {
        m_st[r] = -INFINITY;
        Oacc[r] = (f32x4){0.f, 0.f, 0.f, 0.f};
    }

    const int srow = tid >> 2, sch = tid & 3;

    // prefetch first tile (kt0)
    uint4 pKh0, pKh1, pKl0, pKl1, pVt0, pVt1; float pkn = 0.f;
    {
        const unsigned short* kh = Khi + base + ((size_t)(kt0 * 64 + srow) << 6);
        const unsigned short* kl = Klo + base + ((size_t)(kt0 * 64 + srow) << 6);
        const unsigned short* vt = Vt  + base + (size_t)srow * NN + kt0 * 64;
        pKh0 = *(const uint4*)(kh + sch * 8);  pKh1 = *(const uint4*)(kh + sch * 8 + 32);
        pKl0 = *(const uint4*)(kl + sch * 8);  pKl1 = *(const uint4*)(kl + sch * 8 + 32);
        pVt0 = *(const uint4*)(vt + sch * 8);  pVt1 = *(const uint4*)(vt + sch * 8 + 32);
        if (tid < 64) pkn = KN[(size_t)bh * NN + kt0 * 64 + tid];
    }

    __syncthreads();   // qn_s visible

    for (int kt = kt0; kt < kend; ++kt) {
        // ---- commit prefetched tile: [chunk][row][8] layout ----
        *(uint4*)&Kh_s[(sch << 9) + (srow << 3)]       = pKh0;
        *(uint4*)&Kh_s[((sch + 4) << 9) + (srow << 3)] = pKh1;
        *(uint4*)&Kl_s[(sch << 9) + (srow << 3)]       = pKl0;
        *(uint4*)&Kl_s[((sch + 4) << 9) + (srow << 3)] = pKl1;
        *(uint4*)&Vt_s[(sch << 9) + (srow << 3)]       = pVt0;
        *(uint4*)&Vt_s[((sch + 4) << 9) + (srow << 3)] = pVt1;
        if (tid < 64) kn_s[tid] = pkn;
        __syncthreads();

        // ---- prefetch tile kt+1 (in flight during compute) ----
        if (kt + 1 < kend) {
            const unsigned short* kh = Khi + base + ((size_t)((kt + 1) * 64 + srow) << 6);
            const unsigned short* kl = Klo + base + ((size_t)((kt + 1) * 64 + srow) << 6);
            const unsigned short* vt = Vt  + base + (size_t)srow * NN + (kt + 1) * 64;
            pKh0 = *(const uint4*)(kh + sch * 8);  pKh1 = *(const uint4*)(kh + sch * 8 + 32);
            pKl0 = *(const uint4*)(kl + sch * 8);  pKl1 = *(const uint4*)(kl + sch * 8 + 32);
            pVt0 = *(const uint4*)(vt + sch * 8);  pVt1 = *(const uint4*)(vt + sch * 8 + 32);
            if (tid < 64) pkn = KN[(size_t)bh * NN + (kt + 1) * 64 + tid];
        }

        // ---- S = Q K^T (hi/lo compensated), conflict-free frag reads ----
        f32x4 S[4];
        #pragma unroll
        for (int t = 0; t < 4; ++t) {
            f32x4 acc = (f32x4){0.f, 0.f, 0.f, 0.f};
            #pragma unroll
            for (int c2 = 0; c2 < 2; ++c2) {
                const int off = ((c2 * 4 + q4) << 9) + (t << 7) + (lx << 3);
                const bf16x8 kh = *(const bf16x8*)&Kh_s[off];
                const bf16x8 kl = *(const bf16x8*)&Kl_s[off];
                const bf16x8 qh = c2 ? qh1 : qh0;
                const bf16x8 ql = c2 ? ql1 : ql0;
                acc = __builtin_amdgcn_mfma_f32_16x16x32_bf16(qh, kh, acc, 0, 0, 0);
                acc = __builtin_amdgcn_mfma_f32_16x16x32_bf16(qh, kl, acc, 0, 0, 0);
                acc = __builtin_amdgcn_mfma_f32_16x16x32_bf16(ql, kh, acc, 0, 0, 0);
            }
            S[t] = acc;
        }

        // ---- hyperbolic distance -> log2-scores ----
        float qn_r[4];
        #pragma unroll
        for (int r = 0; r < 4; ++r) qn_r[r] = qn_s[w * 16 + q4 * 4 + r];
        const bool diag = (kt == qt);

        float mrow[4] = {-INFINITY, -INFINITY, -INFINITY, -INFINITY};
        #pragma unroll
        for (int t = 0; t < 4; ++t) {
            const float kn = kn_s[t * 16 + lx];
            #pragma unroll
            for (int r = 0; r < 4; ++r) {
                const float sumn = qn_r[r] + kn;
                float diff = fmaxf(fmaf(-2.f, S[t][r], sumn), 0.f);
                float s = -betaL * sqrtf(fmaf(hc, sumn, 1.f) * (diff + 1e-8f));
                const int cc = t * 16 + lx;
                const int rr = w * 16 + q4 * 4 + r;
                if (diag && cc > rr) s = -INFINITY;
                S[t][r] = s;
                mrow[r] = fmaxf(mrow[r], s);
            }
        }

        // ---- online softmax: max-reduce + P write; l comes from MFMA ----
        #pragma unroll
        for (int r = 0; r < 4; ++r) {
            float m = mrow[r];
            m = fmaxf(m, __shfl_xor(m, 1));
            m = fmaxf(m, __shfl_xor(m, 2));
            m = fmaxf(m, __shfl_xor(m, 4));
            m = fmaxf(m, __shfl_xor(m, 8));
            const float mn = fmaxf(m_st[r], m);
            const float al = exp2f(m_st[r] - mn);
            m_st[r] = mn;
            const int prow = ((w * 16 + q4 * 4 + r) << 3) + (lx & 7);
            #pragma unroll
            for (int t = 0; t < 4; ++t) {
                const float p = exp2f(S[t][r] - mn);
                P_s[((t * 2 + (lx >> 3)) << 9) + prow] = f2bf(p);
                Oacc[t][r] *= al;
            }
            Lacc[r] *= al;
        }

        // P_s is wave-local (rows [16w,16w+16)); same-wave DS ops pipe-ordered.
        __builtin_amdgcn_wave_barrier();

        // ---- O += P V ; L += P 1 ----
        #pragma unroll
        for (int c2 = 0; c2 < 2; ++c2) {
            const bf16x8 pa = *(const bf16x8*)&P_s[((c2 * 4 + q4) << 9) + ((w * 16 + lx) << 3)];
            #pragma unroll
            for (int t = 0; t < 4; ++t) {
                const bf16x8 vb = *(const bf16x8*)&Vt_s[((c2 * 4 + q4) << 9) + (t << 7) + (lx << 3)];
                Oacc[t] = __builtin_amdgcn_mfma_f32_16x16x32_bf16(pa, vb, Oacc[t], 0, 0, 0);
            }
            Lacc = __builtin_amdgcn_mfma_f32_16x16x32_bf16(pa, ones, Lacc, 0, 0, 0);
        }
        __syncthreads();   // all waves done reading K/Vt before next commit
    }

    // ---- epilogue: unnormalized fp32 partial + (m2, l) per slot ----
    const int slot = ((bh * 32 + qt) << 2) + c0;
    float* op = Opart + ((size_t)slot << 12);
    #pragma unroll
    for (int r = 0; r < 4; ++r) {
        const int row = w * 16 + q4 * 4 + r;
        #pragma unroll
        for (int t = 0; t < 4; ++t)
            op[row * 64 + t * 16 + lx] = Oacc[t][r];
        if (lx == 0) {
            Mp[slot * 64 + row] = m_st[r];   // log2 domain
            Lp[slot * 64 + row] = Lacc[r];
        }
    }
}

// ---------------------------------------------------------------------------
// Combine <=4 chunk partials per (bh, qt), log2-domain weights.
// ---------------------------------------------------------------------------
__global__ __launch_bounds__(256)
void attn_combine(const float* __restrict__ Opart, const float* __restrict__ Mp,
                  const float* __restrict__ Lp,
                  unsigned short* __restrict__ AOh, unsigned short* __restrict__ AOl)
{
    const int bh = blockIdx.x >> 5, qt = blockIdx.x & 31;
    const int C = (qt >> 3) + 1;
    const int row = threadIdx.x >> 2, qd = threadIdx.x & 3;
    const int slot0 = (bh * 32 + qt) << 2;

    float m = -INFINITY;
    for (int c = 0; c < C; ++c) m = fmaxf(m, Mp[(slot0 + c) * 64 + row]);
    float L = 0.f;
    float o[16];
    #pragma unroll
    for (int j = 0; j < 16; ++j) o[j] = 0.f;

    for (int c = 0; c < C; ++c) {
        const float wgt = exp2f(Mp[(slot0 + c) * 64 + row] - m);
        L += wgt * Lp[(slot0 + c) * 64 + row];
        const float* op = Opart + (((size_t)(slot0 + c)) << 12) + row * 64 + qd * 16;
        #pragma unroll
        for (int j4 = 0; j4 < 4; ++j4) {
            float4 v = *(const float4*)(op + j4 * 4);
            o[j4*4+0] = fmaf(wgt, v.x, o[j4*4+0]);
            o[j4*4+1] = fmaf(wgt, v.y, o[j4*4+1]);
            o[j4*4+2] = fmaf(wgt, v.z, o[j4*4+2]);
            o[j4*4+3] = fmaf(wgt, v.w, o[j4*4+3]);
        }
    }

    const float inv = 1.f / L;
    const size_t obase = (((size_t)bh * NN + qt * 64 + row) << 6) + qd * 16;
    union { unsigned short u[8]; uint4 v; } h2[2], l2[2];
    #pragma unroll
    for (int j = 0; j < 16; ++j) {
        const float ov = o[j] * inv;
        const unsigned short h = f2bf(ov);
        const unsigned short l = f2bf(ov - bf2f(h));
        h2[j >> 3].u[j & 7] = h;
        l2[j >> 3].u[j & 7] = l;
    }
    *(uint4*)(AOh + obase)     = h2[0].v;
    *(uint4*)(AOh + obase + 8) = h2[1].v;
    *(uint4*)(AOl + obase)     = l2[0].v;
    *(uint4*)(AOl + obase + 8) = l2[1].v;
}

// ---------------------------------------------------------------------------
extern "C" void kernel_launch(void* const* d_in, const int* in_sizes, int n_in,
                              void* d_out, int out_size, void* d_ws, size_t ws_size,
                              hipStream_t stream)
{
    const float* x        = (const float*)d_in[0];
    const float* Wq       = (const float*)d_in[1];
    const float* Wk       = (const float*)d_in[2];
    const float* Wv       = (const float*)d_in[3];
    const float* Wo       = (const float*)d_in[4];
    const float* log_c    = (const float*)d_in[5];
    const float* log_beta = (const float*)d_in[6];
    float* out = (float*)d_out;

    unsigned short* p = (unsigned short*)d_ws;
    unsigned short* xh  = p;            p += EE;
    unsigned short* xl  = p;            p += EE;
    unsigned short* wqh = p;            p += WN;
    unsigned short* wql = p;            p += WN;
    unsigned short* wkh = p;            p += WN;
    unsigned short* wkl = p;            p += WN;
    unsigned short* wvh = p;            p += WN;
    unsigned short* wvl = p;            p += WN;
    unsigned short* woh = p;            p += WN;
    unsigned short* wol = p;            p += WN;
    unsigned short* Qhi = p;            p += EE;
    unsigned short* Qlo = p;            p += EE;
    unsigned short* Khi = p;            p += EE;
    unsigned short* Klo = p;            p += EE;
    unsigned short* Vb  = p;            p += EE;
    unsigned short* Vtr = p;            p += EE;
    unsigned short* AOh = p;            p += EE;
    unsigned short* AOl = p;            p += EE;
    float* QN    = (float*)p;
    float* KN    = QN + (size_t)BB * HH * NN;
    float* Opart = KN + (size_t)BB * HH * NN;                 // 2048 x 4096 fp32
    float* Mp    = Opart + (size_t)NSLOT * 64 * 64;
    float* Lp    = Mp + (size_t)NSLOT * 64;

    split_hl   <<<dim3(256, 5), 256, 0, stream>>>(x, Wq, Wk, Wv, Wo,
                                                  xh, xl, wqh, wql, wkh, wkl, wvh, wvl, woh, wol);
    mm_mfma    <<<dim3(MTOT / 64, 4, 3), 256, 0, stream>>>(xh, xl,
                                                  wqh, wql, wkh, wkl, wvh, wvl, 0,
                                                  Qhi, Qlo, Khi, Klo, Vb, nullptr, QN, KN);
    v_transpose<<<dim3(512), 256, 0, stream>>>(Vb, Vtr);
    attn_mfma  <<<dim3(80, 16), 256, 0, stream>>>(Qhi, Qlo, Khi, Klo, Vtr, QN, KN,
                                                  log_c, log_beta, Opart, Mp, Lp);
    attn_combine<<<dim3(512), 256, 0, stream>>>(Opart, Mp, Lp, AOh, AOl);
    mm_mfma    <<<dim3(MTOT / 64, 4, 1), 256, 0, stream>>>(AOh, AOl,
                                                  woh, wol, nullptr, nullptr, nullptr, nullptr, 1,
                                                  nullptr, nullptr, nullptr, nullptr, nullptr, out,
                                                  nullptr, nullptr);
}

// Round 8
// 215.903 us; speedup vs baseline: 1.0190x; 1.0190x over previous
//
#include <hip/hip_runtime.h>
#include <math.h>

#define BB   2
#define NN   2048
#define DDIM 512
#define HH   8
#define DH   64
#define MTOT (BB*NN)      // 4096
#define LDK  72           // ushort stride (v_transpose scratch only)
#define EE   (BB*HH*NN*DH)   // 2,097,152 elems per Q/K/V-like array
#define WN   (DDIM*DDIM)     // 262,144 elems per weight
#define CPB  144             // chunk-blocks per bh (sum over qt of ceil((qt+1)/4))
#define NSLOT (BB*HH*CPB)    // 2304 partial slots

typedef __attribute__((ext_vector_type(8))) short bf16x8;   // 8 bf16 = 4 VGPRs
typedef __attribute__((ext_vector_type(4))) float f32x4;

__device__ __forceinline__ float softplus_f(float x) {
    return x > 20.f ? x : log1pf(expf(x));
}
__device__ __forceinline__ unsigned short f2bf(float x) {   // round-to-nearest-even
    union { float f; unsigned u; } v; v.f = x;
    unsigned r = v.u + 0x7fffu + ((v.u >> 16) & 1u);
    return (unsigned short)(r >> 16);
}
__device__ __forceinline__ float bf2f(unsigned short h) {
    union { unsigned u; float f; } v; v.u = ((unsigned)h) << 16; return v.f;
}

// ---------------------------------------------------------------------------
// Split fp32 -> bf16 hi/lo pairs. blockIdx.y selects {x, Wq, Wk, Wv, Wo}.
// ---------------------------------------------------------------------------
__global__ __launch_bounds__(256)
void split_hl(const float* __restrict__ x,  const float* __restrict__ Wq,
              const float* __restrict__ Wk, const float* __restrict__ Wv,
              const float* __restrict__ Wo,
              unsigned short* __restrict__ xh,  unsigned short* __restrict__ xl,
              unsigned short* __restrict__ wqh, unsigned short* __restrict__ wql,
              unsigned short* __restrict__ wkh, unsigned short* __restrict__ wkl,
              unsigned short* __restrict__ wvh, unsigned short* __restrict__ wvl,
              unsigned short* __restrict__ woh, unsigned short* __restrict__ wol)
{
    const float* src; unsigned short *dh, *dl; int nq;
    switch (blockIdx.y) {
        case 0:  src = x;  dh = xh;  dl = xl;  nq = EE / 4; break;
        case 1:  src = Wq; dh = wqh; dl = wql; nq = WN / 4; break;
        case 2:  src = Wk; dh = wkh; dl = wkl; nq = WN / 4; break;
        case 3:  src = Wv; dh = wvh; dl = wvl; nq = WN / 4; break;
        default: src = Wo; dh = woh; dl = wol; nq = WN / 4; break;
    }
    for (int i = blockIdx.x * 256 + threadIdx.x; i < nq; i += gridDim.x * 256) {
        float4 v = *(const float4*)(src + 4 * (size_t)i);
        ushort4 h, l;
        h.x = f2bf(v.x); l.x = f2bf(v.x - bf2f(h.x));
        h.y = f2bf(v.y); l.y = f2bf(v.y - bf2f(h.y));
        h.z = f2bf(v.z); l.z = f2bf(v.z - bf2f(h.z));
        h.w = f2bf(v.w); l.w = f2bf(v.w - bf2f(h.w));
        *(ushort4*)(dh + 4 * (size_t)i) = h;
        *(ushort4*)(dl + 4 * (size_t)i) = l;
    }
}

// ---------------------------------------------------------------------------
// Unified hi/lo-compensated bf16 MFMA GEMM, templated on N-tile.
// NT=128: proj (768 blocks, 3/CU, norms fused, wave spans one head).
// NT=64:  out-proj (512 blocks, 2/CU — round-7's 256-block 1/CU grid was
//         pure latency). 64-row M-tile, BK=32, register prefetch.
// ---------------------------------------------------------------------------
template<int NT>
__global__ __launch_bounds__(256, 3)
void mm_mfma(const unsigned short* __restrict__ Ahg, const unsigned short* __restrict__ Alg,
             const unsigned short* __restrict__ W0h, const unsigned short* __restrict__ W0l,
             const unsigned short* __restrict__ W1h, const unsigned short* __restrict__ W1l,
             const unsigned short* __restrict__ W2h, const unsigned short* __restrict__ W2l,
             const int is_out,
             unsigned short* __restrict__ Qhi, unsigned short* __restrict__ Qlo,
             unsigned short* __restrict__ Khi, unsigned short* __restrict__ Klo,
             unsigned short* __restrict__ Vb, float* __restrict__ Outp,
             float* __restrict__ QN, float* __restrict__ KN)
{
    const int mode = is_out ? 3 : (int)blockIdx.z;
    const unsigned short* Wh = (mode == 1) ? W1h : ((mode == 2) ? W2h : W0h);
    const unsigned short* Wl = (mode == 1) ? W1l : ((mode == 2) ? W2l : W0l);
    const int m0 = blockIdx.x * 64, n0 = blockIdx.y * NT;

    constexpr int NTT = NT / 32;    // n-tiles per wave
    constexpr int NW  = NT / 2;     // cols per wave
    constexpr int KQS = NT * 8;     // Bh_s kq stride (ushorts)

    __shared__ unsigned short Ah_s[4 * 64 * 8];    // [kq][64][8]
    __shared__ unsigned short Al_s[4 * 64 * 8];
    __shared__ unsigned short Bh_s[4 * NT * 8];    // [kq][NT][8]
    __shared__ unsigned short Bl_s[4 * NT * 8];

    const int tid  = threadIdx.x;
    const int lane = tid & 63, lx = lane & 15, q4 = lane >> 4;
    const int w = tid >> 6, wm = w & 1, wn = w >> 1;
    const int rowA = tid & 63, kqA = tid >> 6;

    int rowB, kbB;
    if (NT == 128) { rowB = tid & 127; kbB = tid >> 7; }
    else           { rowB = tid & 63;  kbB = tid >> 6; }

    f32x4 acc[2][NTT];
    #pragma unroll
    for (int mt = 0; mt < 2; ++mt)
        #pragma unroll
        for (int nt = 0; nt < NTT; ++nt)
            acc[mt][nt] = (f32x4){0.f, 0.f, 0.f, 0.f};

    const int am = m0 + rowA;
    const int ab = am >> 11, an = am & 2047;
    const size_t brow = (size_t)(n0 + rowB) * DDIM;

    uint4 rah, ral, rbh0, rbl0, rbh1, rbl1;
    {
        const int e = kqA * 8;
        size_t aoff = (mode == 3)
            ? ((((size_t)(ab * HH + (e >> 6)) * NN + an) << 6) + (e & 63))
            : ((size_t)am * DDIM + e);
        rah = *(const uint4*)(Ahg + aoff);
        ral = *(const uint4*)(Alg + aoff);
        const int eb = kbB * 8;
        rbh0 = *(const uint4*)(Wh + brow + eb);
        rbl0 = *(const uint4*)(Wl + brow + eb);
        if (NT == 128) {
            rbh1 = *(const uint4*)(Wh + brow + eb + 16);
            rbl1 = *(const uint4*)(Wl + brow + eb + 16);
        }
    }

    for (int k0 = 0; k0 < DDIM; k0 += 32) {
        __syncthreads();    // previous compute done
        *(uint4*)&Ah_s[(kqA << 9) + (rowA << 3)] = rah;
        *(uint4*)&Al_s[(kqA << 9) + (rowA << 3)] = ral;
        *(uint4*)&Bh_s[kbB * KQS + (rowB << 3)] = rbh0;
        *(uint4*)&Bl_s[kbB * KQS + (rowB << 3)] = rbl0;
        if (NT == 128) {
            *(uint4*)&Bh_s[(kbB + 2) * KQS + (rowB << 3)] = rbh1;
            *(uint4*)&Bl_s[(kbB + 2) * KQS + (rowB << 3)] = rbl1;
        }
        __syncthreads();    // staged tile visible

        if (k0 + 32 < DDIM) {   // prefetch next K-slice (overlaps MFMAs)
            const int e = k0 + 32 + kqA * 8;
            size_t aoff = (mode == 3)
                ? ((((size_t)(ab * HH + (e >> 6)) * NN + an) << 6) + (e & 63))
                : ((size_t)am * DDIM + e);
            rah = *(const uint4*)(Ahg + aoff);
            ral = *(const uint4*)(Alg + aoff);
            const int eb = k0 + 32 + kbB * 8;
            rbh0 = *(const uint4*)(Wh + brow + eb);
            rbl0 = *(const uint4*)(Wl + brow + eb);
            if (NT == 128) {
                rbh1 = *(const uint4*)(Wh + brow + eb + 16);
                rbl1 = *(const uint4*)(Wl + brow + eb + 16);
            }
        }

        bf16x8 fah[2], fal[2], fbh[NTT], fbl[NTT];
        #pragma unroll
        for (int mt = 0; mt < 2; ++mt) {
            const int off = (q4 << 9) + ((wm * 32 + mt * 16 + lx) << 3);
            fah[mt] = *(const bf16x8*)&Ah_s[off];
            fal[mt] = *(const bf16x8*)&Al_s[off];
        }
        #pragma unroll
        for (int nt = 0; nt < NTT; ++nt) {
            const int off = q4 * KQS + ((wn * NW + nt * 16 + lx) << 3);
            fbh[nt] = *(const bf16x8*)&Bh_s[off];
            fbl[nt] = *(const bf16x8*)&Bl_s[off];
        }
        #pragma unroll
        for (int mt = 0; mt < 2; ++mt)
            #pragma unroll
            for (int nt = 0; nt < NTT; ++nt) {
                acc[mt][nt] = __builtin_amdgcn_mfma_f32_16x16x32_bf16(fah[mt], fbh[nt], acc[mt][nt], 0, 0, 0);
                acc[mt][nt] = __builtin_amdgcn_mfma_f32_16x16x32_bf16(fah[mt], fbl[nt], acc[mt][nt], 0, 0, 0);
                acc[mt][nt] = __builtin_amdgcn_mfma_f32_16x16x32_bf16(fal[mt], fbh[nt], acc[mt][nt], 0, 0, 0);
            }
    }

    // ---- fused row norms (modes 0/1; NT=128 only — wave spans one head) ----
    if (NT == 128 && (mode == 0 || mode == 1)) {
        float* Np = (mode == 0) ? QN : KN;
        const int head = (n0 + wn * 64) >> 6;
        #pragma unroll
        for (int mt = 0; mt < 2; ++mt)
            #pragma unroll
            for (int r = 0; r < 4; ++r) {
                float s = 0.f;
                #pragma unroll
                for (int nt = 0; nt < NTT; ++nt) s = fmaf(acc[mt][nt][r], acc[mt][nt][r], s);
                s += __shfl_xor(s, 1);
                s += __shfl_xor(s, 2);
                s += __shfl_xor(s, 4);
                s += __shfl_xor(s, 8);
                if (lx == 0) {
                    const int m = m0 + wm * 32 + mt * 16 + q4 * 4 + r;
                    Np[(size_t)((m >> 11) * HH + head) * NN + (m & 2047)] = s;
                }
            }
    }

    // epilogue: C row m = q4*4+reg, col j = lx (verified mapping)
    #pragma unroll
    for (int mt = 0; mt < 2; ++mt) {
        #pragma unroll
        for (int r = 0; r < 4; ++r) {
            const int m = m0 + wm * 32 + mt * 16 + q4 * 4 + r;
            const int b = m >> 11, n2 = m & 2047;
            #pragma unroll
            for (int nt = 0; nt < NTT; ++nt) {
                const int j = n0 + wn * NW + nt * 16 + lx;
                const float v = acc[mt][nt][r];
                if (mode == 3) {
                    Outp[(size_t)m * DDIM + j] = v;
                } else {
                    const size_t idx = (((size_t)(b * HH + (j >> 6)) * NN + n2) << 6) + (j & 63);
                    if (mode == 2) {
                        Vb[idx] = f2bf(v);
                    } else {
                        const unsigned short h = f2bf(v);
                        const unsigned short l = f2bf(v - bf2f(h));
                        if (mode == 0) { Qhi[idx] = h; Qlo[idx] = l; }
                        else           { Khi[idx] = h; Klo[idx] = l; }
                    }
                }
            }
        }
    }
}

// ---------------------------------------------------------------------------
// V transpose: Vb [B,H,N,64] bf16 -> Vt [B,H,64,N] bf16
// ---------------------------------------------------------------------------
__global__ __launch_bounds__(256)
void v_transpose(const unsigned short* __restrict__ Vb, unsigned short* __restrict__ Vt)
{
    __shared__ unsigned short T[64 * LDK];
    const int id = blockIdx.x;          // 512 = 16 bh * 32 n-tiles
    const int bh = id >> 5, nt = id & 31;
    const size_t ibase = (((size_t)bh * NN + nt * 64) << 6);
    const int row = threadIdx.x >> 2, ch = threadIdx.x & 3;

    #pragma unroll
    for (int half = 0; half < 2; ++half) {
        const int col = ch * 8 + half * 32;
        *(uint4*)&T[row * LDK + col] = *(const uint4*)(Vb + ibase + (row << 6) + col);
    }
    __syncthreads();

    const size_t obase = (size_t)bh * 64 * NN;
    #pragma unroll
    for (int half = 0; half < 2; ++half) {
        const int col = ch * 8 + half * 32;
        union { unsigned short u[8]; uint4 v; } tmp;
        #pragma unroll
        for (int j = 0; j < 8; ++j) tmp.u[j] = T[(col + j) * LDK + row];
        *(uint4*)(Vt + obase + (size_t)row * NN + nt * 64 + col) = tmp.v;
    }
}

// ---------------------------------------------------------------------------
// MFMA flash attention, split-K with chunk length <= 4 k-tiles:
// C(qt) = ceil((qt+1)/4) chunks -> 144 blocks/bh, 2304 total (9/CU queued,
// uniform 2-4 iter lifetimes; round-7's 1280 blocks at 1-8 iters left the
// machine at 2 blocks/CU). Partials fp32 to workspace; combine merges <=8.
// ---------------------------------------------------------------------------
__global__ __launch_bounds__(256, 4)
void attn_mfma(const unsigned short* __restrict__ Qhi, const unsigned short* __restrict__ Qlo,
               const unsigned short* __restrict__ Khi, const unsigned short* __restrict__ Klo,
               const unsigned short* __restrict__ Vt,
               const float* __restrict__ QN, const float* __restrict__ KN,
               const float* __restrict__ pLC, const float* __restrict__ pLB,
               float* __restrict__ Opart, float* __restrict__ Mp, float* __restrict__ Lp)
{
    __shared__ unsigned short Kh_s[8 * 64 * 8];   // [dq][key][8]
    __shared__ unsigned short Kl_s[8 * 64 * 8];
    __shared__ unsigned short Vt_s[8 * 64 * 8];   // [keyq][d][8]
    __shared__ unsigned short P_s [8 * 64 * 8];   // [keyq][row][8]
    __shared__ float kn_s[64];
    __shared__ float qn_s[64];

    // decode (qt, chunk): group g = qt>>2 has C=g+1 chunks/qt, base 2g(g+1)
    const int idx = blockIdx.x;
    const int g   = (idx >= 112) ? 7 : (idx >= 84) ? 6 : (idx >= 60) ? 5 :
                    (idx >= 40) ? 4 : (idx >= 24) ? 3 : (idx >= 12) ? 2 :
                    (idx >= 4)  ? 1 : 0;
    const int rem = idx - 2 * g * (g + 1);
    const int C   = g + 1;
    const int qt  = g * 4 + rem / C;
    const int c0  = rem % C;
    const int bh  = blockIdx.y;
    const int nk  = qt + 1;
    const int kt0  = (c0 * nk) / C;        // balanced ranges (len 2..4)
    const int kend = ((c0 + 1) * nk) / C;

    const int tid  = threadIdx.x;
    const int w    = tid >> 6;
    const int lane = tid & 63;
    const int lx   = lane & 15;
    const int q4   = lane >> 4;

    const float hc    = softplus_f(pLC[0]);
    const float betaL = (softplus_f(pLB[0]) + 0.5f) * 1.44269504f;  // log2 domain

    const size_t base = ((size_t)bh * NN) << 6;

    // all-ones bf16 fragment for l-via-MFMA
    union { unsigned short u[8]; bf16x8 v; } ones_u;
    #pragma unroll
    for (int j = 0; j < 8; ++j) ones_u.u[j] = 0x3F80;
    const bf16x8 ones = ones_u.v;

    // Q fragments (A-layout: m=lx, k=q4*8+j), registers for whole block
    const unsigned short* qrh = Qhi + base + ((size_t)(qt * 64 + w * 16 + lx) << 6) + q4 * 8;
    const unsigned short* qrl = Qlo + base + ((size_t)(qt * 64 + w * 16 + lx) << 6) + q4 * 8;
    const bf16x8 qh0 = *(const bf16x8*)(qrh);
    const bf16x8 qh1 = *(const bf16x8*)(qrh + 32);
    const bf16x8 ql0 = *(const bf16x8*)(qrl);
    const bf16x8 ql1 = *(const bf16x8*)(qrl + 32);

    if (tid < 64) qn_s[tid] = QN[(size_t)bh * NN + qt * 64 + tid];

    f32x4 Oacc[4];
    f32x4 Lacc = (f32x4){0.f, 0.f, 0.f, 0.f};
    float m_st[4];
    #pragma unroll
    for (int r = 0; r < 4; ++r) {
        m_st[r] = -INFINITY;
        Oacc[r] = (f32x4){0.f, 0.f, 0.f, 0.f};
    }

    const int srow = tid >> 2, sch = tid & 3;

    // prefetch first tile (kt0)
    uint4 pKh0, pKh1, pKl0, pKl1, pVt0, pVt1; float pkn = 0.f;
    {
        const unsigned short* kh = Khi + base + ((size_t)(kt0 * 64 + srow) << 6);
        const unsigned short* kl = Klo + base + ((size_t)(kt0 * 64 + srow) << 6);
        const unsigned short* vt = Vt  + base + (size_t)srow * NN + kt0 * 64;
        pKh0 = *(const uint4*)(kh + sch * 8);  pKh1 = *(const uint4*)(kh + sch * 8 + 32);
        pKl0 = *(const uint4*)(kl + sch * 8);  pKl1 = *(const uint4*)(kl + sch * 8 + 32);
        pVt0 = *(const uint4*)(vt + sch * 8);  pVt1 = *(const uint4*)(vt + sch * 8 + 32);
        if (tid < 64) pkn = KN[(size_t)bh * NN + kt0 * 64 + tid];
    }

    __syncthreads();   // qn_s visible

    for (int kt = kt0; kt < kend; ++kt) {
        // ---- commit prefetched tile: [chunk][row][8] layout ----
        *(uint4*)&Kh_s[(sch << 9) + (srow << 3)]       = pKh0;
        *(uint4*)&Kh_s[((sch + 4) << 9) + (srow << 3)] = pKh1;
        *(uint4*)&Kl_s[(sch << 9) + (srow << 3)]       = pKl0;
        *(uint4*)&Kl_s[((sch + 4) << 9) + (srow << 3)] = pKl1;
        *(uint4*)&Vt_s[(sch << 9) + (srow << 3)]       = pVt0;
        *(uint4*)&Vt_s[((sch + 4) << 9) + (srow << 3)] = pVt1;
        if (tid < 64) kn_s[tid] = pkn;
        __syncthreads();

        // ---- prefetch tile kt+1 (in flight during compute) ----
        if (kt + 1 < kend) {
            const unsigned short* kh = Khi + base + ((size_t)((kt + 1) * 64 + srow) << 6);
            const unsigned short* kl = Klo + base + ((size_t)((kt + 1) * 64 + srow) << 6);
            const unsigned short* vt = Vt  + base + (size_t)srow * NN + (kt + 1) * 64;
            pKh0 = *(const uint4*)(kh + sch * 8);  pKh1 = *(const uint4*)(kh + sch * 8 + 32);
            pKl0 = *(const uint4*)(kl + sch * 8);  pKl1 = *(const uint4*)(kl + sch * 8 + 32);
            pVt0 = *(const uint4*)(vt + sch * 8);  pVt1 = *(const uint4*)(vt + sch * 8 + 32);
            if (tid < 64) pkn = KN[(size_t)bh * NN + (kt + 1) * 64 + tid];
        }

        // ---- S = Q K^T (hi/lo compensated) ----
        f32x4 S[4];
        #pragma unroll
        for (int t = 0; t < 4; ++t) {
            f32x4 acc = (f32x4){0.f, 0.f, 0.f, 0.f};
            #pragma unroll
            for (int c2 = 0; c2 < 2; ++c2) {
                const int off = ((c2 * 4 + q4) << 9) + (t << 7) + (lx << 3);
                const bf16x8 kh = *(const bf16x8*)&Kh_s[off];
                const bf16x8 kl = *(const bf16x8*)&Kl_s[off];
                const bf16x8 qh = c2 ? qh1 : qh0;
                const bf16x8 ql = c2 ? ql1 : ql0;
                acc = __builtin_amdgcn_mfma_f32_16x16x32_bf16(qh, kh, acc, 0, 0, 0);
                acc = __builtin_amdgcn_mfma_f32_16x16x32_bf16(qh, kl, acc, 0, 0, 0);
                acc = __builtin_amdgcn_mfma_f32_16x16x32_bf16(ql, kh, acc, 0, 0, 0);
            }
            S[t] = acc;
        }

        // ---- hyperbolic distance -> log2-scores ----
        float qn_r[4];
        #pragma unroll
        for (int r = 0; r < 4; ++r) qn_r[r] = qn_s[w * 16 + q4 * 4 + r];
        const bool diag = (kt == qt);

        float mrow[4] = {-INFINITY, -INFINITY, -INFINITY, -INFINITY};
        #pragma unroll
        for (int t = 0; t < 4; ++t) {
            const float kn = kn_s[t * 16 + lx];
            #pragma unroll
            for (int r = 0; r < 4; ++r) {
                const float sumn = qn_r[r] + kn;
                float diff = fmaxf(fmaf(-2.f, S[t][r], sumn), 0.f);
                float s = -betaL * sqrtf(fmaf(hc, sumn, 1.f) * (diff + 1e-8f));
                const int cc = t * 16 + lx;
                const int rr = w * 16 + q4 * 4 + r;
                if (diag && cc > rr) s = -INFINITY;
                S[t][r] = s;
                mrow[r] = fmaxf(mrow[r], s);
            }
        }

        // ---- online softmax: max-reduce + P write; l via MFMA ----
        #pragma unroll
        for (int r = 0; r < 4; ++r) {
            float m = mrow[r];
            m = fmaxf(m, __shfl_xor(m, 1));
            m = fmaxf(m, __shfl_xor(m, 2));
            m = fmaxf(m, __shfl_xor(m, 4));
            m = fmaxf(m, __shfl_xor(m, 8));
            const float mn = fmaxf(m_st[r], m);
            const float al = exp2f(m_st[r] - mn);
            m_st[r] = mn;
            const int prow = ((w * 16 + q4 * 4 + r) << 3) + (lx & 7);
            #pragma unroll
            for (int t = 0; t < 4; ++t) {
                const float p = exp2f(S[t][r] - mn);
                P_s[((t * 2 + (lx >> 3)) << 9) + prow] = f2bf(p);
                Oacc[t][r] *= al;
            }
            Lacc[r] *= al;
        }

        // P_s is wave-local (rows [16w,16w+16)); same-wave DS ops pipe-ordered.
        __builtin_amdgcn_wave_barrier();

        // ---- O += P V ; L += P 1 ----
        #pragma unroll
        for (int c2 = 0; c2 < 2; ++c2) {
            const bf16x8 pa = *(const bf16x8*)&P_s[((c2 * 4 + q4) << 9) + ((w * 16 + lx) << 3)];
            #pragma unroll
            for (int t = 0; t < 4; ++t) {
                const bf16x8 vb = *(const bf16x8*)&Vt_s[((c2 * 4 + q4) << 9) + (t << 7) + (lx << 3)];
                Oacc[t] = __builtin_amdgcn_mfma_f32_16x16x32_bf16(pa, vb, Oacc[t], 0, 0, 0);
            }
            Lacc = __builtin_amdgcn_mfma_f32_16x16x32_bf16(pa, ones, Lacc, 0, 0, 0);
        }
        __syncthreads();   // all waves done reading K/Vt before next commit
    }

    // ---- epilogue: unnormalized fp32 partial + (m2, l); slot = per-bh idx ----
    const int slot = bh * CPB + idx;
    float* op = Opart + ((size_t)slot << 12);
    #pragma unroll
    for (int r = 0; r < 4; ++r) {
        const int row = w * 16 + q4 * 4 + r;
        #pragma unroll
        for (int t = 0; t < 4; ++t)
            op[row * 64 + t * 16 + lx] = Oacc[t][r];
        if (lx == 0) {
            Mp[slot * 64 + row] = m_st[r];   // log2 domain
            Lp[slot * 64 + row] = Lacc[r];
        }
    }
}

// ---------------------------------------------------------------------------
// Combine <=8 chunk partials per (bh, qt), log2-domain weights.
// ---------------------------------------------------------------------------
__global__ __launch_bounds__(256)
void attn_combine(const float* __restrict__ Opart, const float* __restrict__ Mp,
                  const float* __restrict__ Lp,
                  unsigned short* __restrict__ AOh, unsigned short* __restrict__ AOl)
{
    const int bh = blockIdx.x >> 5, qt = blockIdx.x & 31;
    const int g = qt >> 2, C = g + 1;
    const int first = 2 * g * (g + 1) + (qt & 3) * C;
    const int row = threadIdx.x >> 2, qd = threadIdx.x & 3;
    const int slot0 = bh * CPB + first;

    float m = -INFINITY;
    for (int c = 0; c < C; ++c) m = fmaxf(m, Mp[(slot0 + c) * 64 + row]);
    float L = 0.f;
    float o[16];
    #pragma unroll
    for (int j = 0; j < 16; ++j) o[j] = 0.f;

    for (int c = 0; c < C; ++c) {
        const float wgt = exp2f(Mp[(slot0 + c) * 64 + row] - m);
        L += wgt * Lp[(slot0 + c) * 64 + row];
        const float* op = Opart + (((size_t)(slot0 + c)) << 12) + row * 64 + qd * 16;
        #pragma unroll
        for (int j4 = 0; j4 < 4; ++j4) {
            float4 v = *(const float4*)(op + j4 * 4);
            o[j4*4+0] = fmaf(wgt, v.x, o[j4*4+0]);
            o[j4*4+1] = fmaf(wgt, v.y, o[j4*4+1]);
            o[j4*4+2] = fmaf(wgt, v.z, o[j4*4+2]);
            o[j4*4+3] = fmaf(wgt, v.w, o[j4*4+3]);
        }
    }

    const float inv = 1.f / L;
    const size_t obase = (((size_t)bh * NN + qt * 64 + row) << 6) + qd * 16;
    union { unsigned short u[8]; uint4 v; } h2[2], l2[2];
    #pragma unroll
    for (int j = 0; j < 16; ++j) {
        const float ov = o[j] * inv;
        const unsigned short h = f2bf(ov);
        const unsigned short l = f2bf(ov - bf2f(h));
        h2[j >> 3].u[j & 7] = h;
        l2[j >> 3].u[j & 7] = l;
    }
    *(uint4*)(AOh + obase)     = h2[0].v;
    *(uint4*)(AOh + obase + 8) = h2[1].v;
    *(uint4*)(AOl + obase)     = l2[0].v;
    *(uint4*)(AOl + obase + 8) = l2[1].v;
}

// ---------------------------------------------------------------------------
extern "C" void kernel_launch(void* const* d_in, const int* in_sizes, int n_in,
                              void* d_out, int out_size, void* d_ws, size_t ws_size,
                              hipStream_t stream)
{
    const float* x        = (const float*)d_in[0];
    const float* Wq       = (const float*)d_in[1];
    const float* Wk       = (const float*)d_in[2];
    const float* Wv       = (const float*)d_in[3];
    const float* Wo       = (const float*)d_in[4];
    const float* log_c    = (const float*)d_in[5];
    const float* log_beta = (const float*)d_in[6];
    float* out = (float*)d_out;

    unsigned short* p = (unsigned short*)d_ws;
    unsigned short* xh  = p;            p += EE;
    unsigned short* xl  = p;            p += EE;
    unsigned short* wqh = p;            p += WN;
    unsigned short* wql = p;            p += WN;
    unsigned short* wkh = p;            p += WN;
    unsigned short* wkl = p;            p += WN;
    unsigned short* wvh = p;            p += WN;
    unsigned short* wvl = p;            p += WN;
    unsigned short* woh = p;            p += WN;
    unsigned short* wol = p;            p += WN;
    unsigned short* Qhi = p;            p += EE;
    unsigned short* Qlo = p;            p += EE;
    unsigned short* Khi = p;            p += EE;
    unsigned short* Klo = p;            p += EE;
    unsigned short* Vb  = p;            p += EE;
    unsigned short* Vtr = p;            p += EE;
    unsigned short* AOh = p;            p += EE;
    unsigned short* AOl = p;            p += EE;
    float* QN    = (float*)p;
    float* KN    = QN + (size_t)BB * HH * NN;
    float* Opart = KN + (size_t)BB * HH * NN;                 // 2304 x 4096 fp32
    float* Mp    = Opart + (size_t)NSLOT * 64 * 64;
    float* Lp    = Mp + (size_t)NSLOT * 64;

    split_hl   <<<dim3(256, 5), 256, 0, stream>>>(x, Wq, Wk, Wv, Wo,
                                                  xh, xl, wqh, wql, wkh, wkl, wvh, wvl, woh, wol);
    mm_mfma<128><<<dim3(MTOT / 64, DDIM / 128, 3), 256, 0, stream>>>(xh, xl,
                                                  wqh, wql, wkh, wkl, wvh, wvl, 0,
                                                  Qhi, Qlo, Khi, Klo, Vb, nullptr, QN, KN);
    v_transpose<<<dim3(512), 256, 0, stream>>>(Vb, Vtr);
    attn_mfma  <<<dim3(CPB, 16), 256, 0, stream>>>(Qhi, Qlo, Khi, Klo, Vtr, QN, KN,
                                                   log_c, log_beta, Opart, Mp, Lp);
    attn_combine<<<dim3(512), 256, 0, stream>>>(Opart, Mp, Lp, AOh, AOl);
    mm_mfma<64><<<dim3(MTOT / 64, DDIM / 64, 1), 256, 0, stream>>>(AOh, AOl,
                                                  woh, wol, nullptr, nullptr, nullptr, nullptr, 1,
                                                  nullptr, nullptr, nullptr, nullptr, nullptr, out,
                                                  nullptr, nullptr);
}

// Round 9
// 206.632 us; speedup vs baseline: 1.0647x; 1.0449x over previous
//
#include <hip/hip_runtime.h>
#include <math.h>

#define BB   2
#define NN   2048
#define DDIM 512
#define HH   8
#define DH   64
#define MTOT (BB*NN)      // 4096
#define EE   (BB*HH*NN*DH)   // 2,097,152 elems per Q/K/V-like array
#define CPB  144             // chunk-blocks per bh (sum over qt of ceil((qt+1)/4))
#define NSLOT (BB*HH*CPB)    // 2304 partial slots

typedef __attribute__((ext_vector_type(8))) short bf16x8;   // 8 bf16 = 4 VGPRs
typedef __attribute__((ext_vector_type(4))) float f32x4;

__device__ __forceinline__ float softplus_f(float x) {
    return x > 20.f ? x : log1pf(expf(x));
}
__device__ __forceinline__ unsigned short f2bf(float x) {   // round-to-nearest-even
    union { float f; unsigned u; } v; v.f = x;
    unsigned r = v.u + 0x7fffu + ((v.u >> 16) & 1u);
    return (unsigned short)(r >> 16);
}
__device__ __forceinline__ float bf2f(unsigned short h) {
    union { unsigned u; float f; } v; v.u = ((unsigned)h) << 16; return v.f;
}
__device__ __forceinline__ void split4(float4 v, ushort4& h, ushort4& l) {
    h.x = f2bf(v.x); l.x = f2bf(v.x - bf2f(h.x));
    h.y = f2bf(v.y); l.y = f2bf(v.y - bf2f(h.y));
    h.z = f2bf(v.z); l.z = f2bf(v.z - bf2f(h.z));
    h.w = f2bf(v.w); l.w = f2bf(v.w - bf2f(h.w));
}

// ---------------------------------------------------------------------------
// Unified hi/lo-compensated bf16 MFMA GEMM with ON-THE-FLY fp32->hi/lo split
// of the staged operands (kills the separate split_hl pass).
// PROJ=true,  NT=128: A = x fp32, W = Wq/Wk/Wv fp32 (blockIdx.z), epilogue ->
//   Qhi/Qlo/Khi/Klo ([B,H,N,dh]) + fused norms, or Vt DIRECTLY TRANSPOSED
//   ([B,H,64,N], kills v_transpose).
// PROJ=false, NT=64: A = AOh/AOl bf16 (combine pre-splits), W = Wo fp32,
//   epilogue -> fp32 out.
// 64-row M-tile, BK=32, register prefetch, [kq][row][8] conflict-free LDS.
// ---------------------------------------------------------------------------
template<int NT, bool PROJ>
__global__ __launch_bounds__(256, 3)
void mm_mfma(const float* __restrict__ Xf,
             const unsigned short* __restrict__ Ahg, const unsigned short* __restrict__ Alg,
             const float* __restrict__ W0, const float* __restrict__ W1,
             const float* __restrict__ W2,
             unsigned short* __restrict__ Qhi, unsigned short* __restrict__ Qlo,
             unsigned short* __restrict__ Khi, unsigned short* __restrict__ Klo,
             unsigned short* __restrict__ Vt, float* __restrict__ Outp,
             float* __restrict__ QN, float* __restrict__ KN)
{
    const int mode = PROJ ? (int)blockIdx.z : 3;
    const float* W = (mode == 1) ? W1 : ((mode == 2) ? W2 : W0);
    const int m0 = blockIdx.x * 64, n0 = blockIdx.y * NT;

    constexpr int NTT = NT / 32;    // n-tiles per wave
    constexpr int NW  = NT / 2;     // cols per wave
    constexpr int KQS = NT * 8;     // B LDS kq stride (ushorts)

    __shared__ unsigned short Ah_s[4 * 64 * 8];    // [kq][64][8]
    __shared__ unsigned short Al_s[4 * 64 * 8];
    __shared__ unsigned short Bh_s[4 * NT * 8];    // [kq][NT][8]
    __shared__ unsigned short Bl_s[4 * NT * 8];

    const int tid  = threadIdx.x;
    const int lane = tid & 63, lx = lane & 15, q4 = lane >> 4;
    const int w = tid >> 6, wm = w & 1, wn = w >> 1;
    const int rowA = tid & 63, kqA = tid >> 6;

    int rowB, kbB;
    if (NT == 128) { rowB = tid & 127; kbB = tid >> 7; }
    else           { rowB = tid & 63;  kbB = tid >> 6; }

    f32x4 acc[2][NTT];
    #pragma unroll
    for (int mt = 0; mt < 2; ++mt)
        #pragma unroll
        for (int nt = 0; nt < NTT; ++nt)
            acc[mt][nt] = (f32x4){0.f, 0.f, 0.f, 0.f};

    const int am = m0 + rowA;
    const int ab = am >> 11, an = am & 2047;
    const size_t brow = (size_t)(n0 + rowB) * DDIM;

    // prefetch registers
    float4 fa0, fa1;            // PROJ A
    uint4  rah, ral;            // !PROJ A (bf16 hi/lo)
    float4 fb0, fb1, fb2, fb3;  // B fp32 (fb2/3 only NT==128)

    {
        const int e = kqA * 8;
        if (PROJ) {
            const float* ap = Xf + (size_t)am * DDIM + e;
            fa0 = *(const float4*)(ap);
            fa1 = *(const float4*)(ap + 4);
        } else {
            const size_t aoff = (((size_t)(ab * HH + (e >> 6)) * NN + an) << 6) + (e & 63);
            rah = *(const uint4*)(Ahg + aoff);
            ral = *(const uint4*)(Alg + aoff);
        }
        const int eb = kbB * 8;
        fb0 = *(const float4*)(W + brow + eb);
        fb1 = *(const float4*)(W + brow + eb + 4);
        if (NT == 128) {
            fb2 = *(const float4*)(W + brow + eb + 16);
            fb3 = *(const float4*)(W + brow + eb + 20);
        }
    }

    for (int k0 = 0; k0 < DDIM; k0 += 32) {
        __syncthreads();    // previous compute done
        if (PROJ) {
            ushort4 h0, l0, h1, l1;
            split4(fa0, h0, l0); split4(fa1, h1, l1);
            const int off = (kqA << 9) + (rowA << 3);
            *(ushort4*)&Ah_s[off]     = h0;  *(ushort4*)&Ah_s[off + 4] = h1;
            *(ushort4*)&Al_s[off]     = l0;  *(ushort4*)&Al_s[off + 4] = l1;
        } else {
            const int off = (kqA << 9) + (rowA << 3);
            *(uint4*)&Ah_s[off] = rah;
            *(uint4*)&Al_s[off] = ral;
        }
        {
            ushort4 h0, l0, h1, l1;
            split4(fb0, h0, l0); split4(fb1, h1, l1);
            const int off = kbB * KQS + (rowB << 3);
            *(ushort4*)&Bh_s[off]     = h0;  *(ushort4*)&Bh_s[off + 4] = h1;
            *(ushort4*)&Bl_s[off]     = l0;  *(ushort4*)&Bl_s[off + 4] = l1;
            if (NT == 128) {
                split4(fb2, h0, l0); split4(fb3, h1, l1);
                const int off2 = (kbB + 2) * KQS + (rowB << 3);
                *(ushort4*)&Bh_s[off2]     = h0;  *(ushort4*)&Bh_s[off2 + 4] = h1;
                *(ushort4*)&Bl_s[off2]     = l0;  *(ushort4*)&Bl_s[off2 + 4] = l1;
            }
        }
        __syncthreads();    // staged tile visible

        if (k0 + 32 < DDIM) {   // prefetch next K-slice (overlaps MFMAs)
            const int e = k0 + 32 + kqA * 8;
            if (PROJ) {
                const float* ap = Xf + (size_t)am * DDIM + e;
                fa0 = *(const float4*)(ap);
                fa1 = *(const float4*)(ap + 4);
            } else {
                const size_t aoff = (((size_t)(ab * HH + (e >> 6)) * NN + an) << 6) + (e & 63);
                rah = *(const uint4*)(Ahg + aoff);
                ral = *(const uint4*)(Alg + aoff);
            }
            const int eb = k0 + 32 + kbB * 8;
            fb0 = *(const float4*)(W + brow + eb);
            fb1 = *(const float4*)(W + brow + eb + 4);
            if (NT == 128) {
                fb2 = *(const float4*)(W + brow + eb + 16);
                fb3 = *(const float4*)(W + brow + eb + 20);
            }
        }

        bf16x8 fah[2], fal[2], fbh[NTT], fbl[NTT];
        #pragma unroll
        for (int mt = 0; mt < 2; ++mt) {
            const int off = (q4 << 9) + ((wm * 32 + mt * 16 + lx) << 3);
            fah[mt] = *(const bf16x8*)&Ah_s[off];
            fal[mt] = *(const bf16x8*)&Al_s[off];
        }
        #pragma unroll
        for (int nt = 0; nt < NTT; ++nt) {
            const int off = q4 * KQS + ((wn * NW + nt * 16 + lx) << 3);
            fbh[nt] = *(const bf16x8*)&Bh_s[off];
            fbl[nt] = *(const bf16x8*)&Bl_s[off];
        }
        #pragma unroll
        for (int mt = 0; mt < 2; ++mt)
            #pragma unroll
            for (int nt = 0; nt < NTT; ++nt) {
                acc[mt][nt] = __builtin_amdgcn_mfma_f32_16x16x32_bf16(fah[mt], fbh[nt], acc[mt][nt], 0, 0, 0);
                acc[mt][nt] = __builtin_amdgcn_mfma_f32_16x16x32_bf16(fah[mt], fbl[nt], acc[mt][nt], 0, 0, 0);
                acc[mt][nt] = __builtin_amdgcn_mfma_f32_16x16x32_bf16(fal[mt], fbh[nt], acc[mt][nt], 0, 0, 0);
            }
    }

    // ---- fused row norms (modes 0/1; wave spans one head at NT=128) ----
    if (PROJ && NT == 128 && (mode == 0 || mode == 1)) {
        float* Np = (mode == 0) ? QN : KN;
        const int head = (n0 + wn * 64) >> 6;
        #pragma unroll
        for (int mt = 0; mt < 2; ++mt)
            #pragma unroll
            for (int r = 0; r < 4; ++r) {
                float s = 0.f;
                #pragma unroll
                for (int nt = 0; nt < NTT; ++nt) s = fmaf(acc[mt][nt][r], acc[mt][nt][r], s);
                s += __shfl_xor(s, 1);
                s += __shfl_xor(s, 2);
                s += __shfl_xor(s, 4);
                s += __shfl_xor(s, 8);
                if (lx == 0) {
                    const int m = m0 + wm * 32 + mt * 16 + q4 * 4 + r;
                    Np[(size_t)((m >> 11) * HH + head) * NN + (m & 2047)] = s;
                }
            }
    }

    // ---- epilogue (C row m = q4*4+reg, col j = lx) ----
    if (mode == 2) {
        // V: write DIRECTLY transposed [B,H,64,N]; 4 consecutive rows (r) pack
        // into one 8-B ushort4 store at (d=j&63, n=m&2047).
        #pragma unroll
        for (int mt = 0; mt < 2; ++mt) {
            const int mb = m0 + wm * 32 + mt * 16 + q4 * 4;
            const int b = mb >> 11, nb = mb & 2047;
            #pragma unroll
            for (int nt = 0; nt < NTT; ++nt) {
                const int j = n0 + wn * NW + nt * 16 + lx;
                ushort4 pv = make_ushort4(f2bf(acc[mt][nt][0]), f2bf(acc[mt][nt][1]),
                                          f2bf(acc[mt][nt][2]), f2bf(acc[mt][nt][3]));
                *(ushort4*)(Vt + ((size_t)(b * HH + (j >> 6)) * 64 + (j & 63)) * NN + nb) = pv;
            }
        }
    } else {
        #pragma unroll
        for (int mt = 0; mt < 2; ++mt) {
            #pragma unroll
            for (int r = 0; r < 4; ++r) {
                const int m = m0 + wm * 32 + mt * 16 + q4 * 4 + r;
                const int b = m >> 11, n2 = m & 2047;
                #pragma unroll
                for (int nt = 0; nt < NTT; ++nt) {
                    const int j = n0 + wn * NW + nt * 16 + lx;
                    const float v = acc[mt][nt][r];
                    if (mode == 3) {
                        Outp[(size_t)m * DDIM + j] = v;
                    } else {
                        const size_t idx = (((size_t)(b * HH + (j >> 6)) * NN + n2) << 6) + (j & 63);
                        const unsigned short h = f2bf(v);
                        const unsigned short l = f2bf(v - bf2f(h));
                        if (mode == 0) { Qhi[idx] = h; Qlo[idx] = l; }
                        else           { Khi[idx] = h; Klo[idx] = l; }
                    }
                }
            }
        }
    }
}

// ---------------------------------------------------------------------------
// MFMA flash attention, split-K (chunks <= 4 k-tiles, 2304 uniform blocks).
// Round-9: staging re-mapped (chunk = wave id, row = lane) so LDS b128 writes
// are lane-contiguous -> conflict-free (round-8 sch<<9 pattern was 4-way).
// ---------------------------------------------------------------------------
__global__ __launch_bounds__(256, 4)
void attn_mfma(const unsigned short* __restrict__ Qhi, const unsigned short* __restrict__ Qlo,
               const unsigned short* __restrict__ Khi, const unsigned short* __restrict__ Klo,
               const unsigned short* __restrict__ Vt,
               const float* __restrict__ QN, const float* __restrict__ KN,
               const float* __restrict__ pLC, const float* __restrict__ pLB,
               float* __restrict__ Opart, float* __restrict__ Mp, float* __restrict__ Lp)
{
    __shared__ unsigned short Kh_s[8 * 64 * 8];   // [dq][key][8]
    __shared__ unsigned short Kl_s[8 * 64 * 8];
    __shared__ unsigned short Vt_s[8 * 64 * 8];   // [keyq][d][8]
    __shared__ unsigned short P_s [8 * 64 * 8];   // [keyq][row][8]
    __shared__ float kn_s[64];
    __shared__ float qn_s[64];

    // decode (qt, chunk): group g = qt>>2 has C=g+1 chunks/qt, base 2g(g+1)
    const int idx = blockIdx.x;
    const int g   = (idx >= 112) ? 7 : (idx >= 84) ? 6 : (idx >= 60) ? 5 :
                    (idx >= 40) ? 4 : (idx >= 24) ? 3 : (idx >= 12) ? 2 :
                    (idx >= 4)  ? 1 : 0;
    const int rem = idx - 2 * g * (g + 1);
    const int C   = g + 1;
    const int qt  = g * 4 + rem / C;
    const int c0  = rem % C;
    const int bh  = blockIdx.y;
    const int nk  = qt + 1;
    const int kt0  = (c0 * nk) / C;        // balanced ranges (len 2..4)
    const int kend = ((c0 + 1) * nk) / C;

    const int tid  = threadIdx.x;
    const int w    = tid >> 6;
    const int lane = tid & 63;
    const int lx   = lane & 15;
    const int q4   = lane >> 4;

    const float hc    = softplus_f(pLC[0]);
    const float betaL = (softplus_f(pLB[0]) + 0.5f) * 1.44269504f;  // log2 domain

    const size_t base = ((size_t)bh * NN) << 6;

    // all-ones bf16 fragment for l-via-MFMA
    union { unsigned short u[8]; bf16x8 v; } ones_u;
    #pragma unroll
    for (int j = 0; j < 8; ++j) ones_u.u[j] = 0x3F80;
    const bf16x8 ones = ones_u.v;

    // Q fragments (A-layout: m=lx, k=q4*8+j), registers for whole block
    const unsigned short* qrh = Qhi + base + ((size_t)(qt * 64 + w * 16 + lx) << 6) + q4 * 8;
    const unsigned short* qrl = Qlo + base + ((size_t)(qt * 64 + w * 16 + lx) << 6) + q4 * 8;
    const bf16x8 qh0 = *(const bf16x8*)(qrh);
    const bf16x8 qh1 = *(const bf16x8*)(qrh + 32);
    const bf16x8 ql0 = *(const bf16x8*)(qrl);
    const bf16x8 ql1 = *(const bf16x8*)(qrl + 32);

    if (tid < 64) qn_s[tid] = QN[(size_t)bh * NN + qt * 64 + tid];

    f32x4 Oacc[4];
    f32x4 Lacc = (f32x4){0.f, 0.f, 0.f, 0.f};
    float m_st[4];
    #pragma unroll
    for (int r = 0; r < 4; ++r) {
        m_st[r] = -INFINITY;
        Oacc[r] = (f32x4){0.f, 0.f, 0.f, 0.f};
    }

    // staging map: chunk = wave id (sc), row = lane (sr) -> LDS writes are
    // lane-contiguous 16 B (conflict-free)
    const int sc = tid >> 6, sr = tid & 63;

    // prefetch first tile (kt0)
    uint4 pKh0, pKh1, pKl0, pKl1, pVt0, pVt1; float pkn = 0.f;
    {
        const unsigned short* kh = Khi + base + ((size_t)(kt0 * 64 + sr) << 6) + sc * 8;
        const unsigned short* kl = Klo + base + ((size_t)(kt0 * 64 + sr) << 6) + sc * 8;
        const unsigned short* vt = Vt  + base + (size_t)sr * NN + kt0 * 64 + sc * 8;
        pKh0 = *(const uint4*)(kh);  pKh1 = *(const uint4*)(kh + 32);
        pKl0 = *(const uint4*)(kl);  pKl1 = *(const uint4*)(kl + 32);
        pVt0 = *(const uint4*)(vt);  pVt1 = *(const uint4*)(vt + 32);
        if (tid < 64) pkn = KN[(size_t)bh * NN + kt0 * 64 + tid];
    }

    __syncthreads();   // qn_s visible

    for (int kt = kt0; kt < kend; ++kt) {
        // ---- commit prefetched tile (conflict-free: lanes contiguous) ----
        const int soff = (sc << 9) + (sr << 3);
        *(uint4*)&Kh_s[soff]                = pKh0;
        *(uint4*)&Kh_s[soff + (4 << 9)]     = pKh1;
        *(uint4*)&Kl_s[soff]                = pKl0;
        *(uint4*)&Kl_s[soff + (4 << 9)]     = pKl1;
        *(uint4*)&Vt_s[soff]                = pVt0;
        *(uint4*)&Vt_s[soff + (4 << 9)]     = pVt1;
        if (tid < 64) kn_s[tid] = pkn;
        __syncthreads();

        // ---- prefetch tile kt+1 (in flight during compute) ----
        if (kt + 1 < kend) {
            const unsigned short* kh = Khi + base + ((size_t)((kt + 1) * 64 + sr) << 6) + sc * 8;
            const unsigned short* kl = Klo + base + ((size_t)((kt + 1) * 64 + sr) << 6) + sc * 8;
            const unsigned short* vt = Vt  + base + (size_t)sr * NN + (kt + 1) * 64 + sc * 8;
            pKh0 = *(const uint4*)(kh);  pKh1 = *(const uint4*)(kh + 32);
            pKl0 = *(const uint4*)(kl);  pKl1 = *(const uint4*)(kl + 32);
            pVt0 = *(const uint4*)(vt);  pVt1 = *(const uint4*)(vt + 32);
            if (tid < 64) pkn = KN[(size_t)bh * NN + (kt + 1) * 64 + tid];
        }

        // ---- S = Q K^T (hi/lo compensated) ----
        f32x4 S[4];
        #pragma unroll
        for (int t = 0; t < 4; ++t) {
            f32x4 acc = (f32x4){0.f, 0.f, 0.f, 0.f};
            #pragma unroll
            for (int c2 = 0; c2 < 2; ++c2) {
                const int off = ((c2 * 4 + q4) << 9) + (t << 7) + (lx << 3);
                const bf16x8 kh = *(const bf16x8*)&Kh_s[off];
                const bf16x8 kl = *(const bf16x8*)&Kl_s[off];
                const bf16x8 qh = c2 ? qh1 : qh0;
                const bf16x8 ql = c2 ? ql1 : ql0;
                acc = __builtin_amdgcn_mfma_f32_16x16x32_bf16(qh, kh, acc, 0, 0, 0);
                acc = __builtin_amdgcn_mfma_f32_16x16x32_bf16(qh, kl, acc, 0, 0, 0);
                acc = __builtin_amdgcn_mfma_f32_16x16x32_bf16(ql, kh, acc, 0, 0, 0);
            }
            S[t] = acc;
        }

        // ---- hyperbolic distance -> log2-scores ----
        float qn_r[4];
        #pragma unroll
        for (int r = 0; r < 4; ++r) qn_r[r] = qn_s[w * 16 + q4 * 4 + r];
        const bool diag = (kt == qt);

        float mrow[4] = {-INFINITY, -INFINITY, -INFINITY, -INFINITY};
        #pragma unroll
        for (int t = 0; t < 4; ++t) {
            const float kn = kn_s[t * 16 + lx];
            #pragma unroll
            for (int r = 0; r < 4; ++r) {
                const float sumn = qn_r[r] + kn;
                float diff = fmaxf(fmaf(-2.f, S[t][r], sumn), 0.f);
                float s = -betaL * sqrtf(fmaf(hc, sumn, 1.f) * (diff + 1e-8f));
                const int cc = t * 16 + lx;
                const int rr = w * 16 + q4 * 4 + r;
                if (diag && cc > rr) s = -INFINITY;
                S[t][r] = s;
                mrow[r] = fmaxf(mrow[r], s);
            }
        }

        // ---- online softmax: max-reduce + P write; l via MFMA ----
        #pragma unroll
        for (int r = 0; r < 4; ++r) {
            float m = mrow[r];
            m = fmaxf(m, __shfl_xor(m, 1));
            m = fmaxf(m, __shfl_xor(m, 2));
            m = fmaxf(m, __shfl_xor(m, 4));
            m = fmaxf(m, __shfl_xor(m, 8));
            const float mn = fmaxf(m_st[r], m);
            const float al = exp2f(m_st[r] - mn);
            m_st[r] = mn;
            const int prow = ((w * 16 + q4 * 4 + r) << 3) + (lx & 7);
            #pragma unroll
            for (int t = 0; t < 4; ++t) {
                const float p = exp2f(S[t][r] - mn);
                P_s[((t * 2 + (lx >> 3)) << 9) + prow] = f2bf(p);
                Oacc[t][r] *= al;
            }
            Lacc[r] *= al;
        }

        // P_s is wave-local (rows [16w,16w+16)); same-wave DS ops pipe-ordered.
        __builtin_amdgcn_wave_barrier();

        // ---- O += P V ; L += P 1 ----
        #pragma unroll
        for (int c2 = 0; c2 < 2; ++c2) {
            const bf16x8 pa = *(const bf16x8*)&P_s[((c2 * 4 + q4) << 9) + ((w * 16 + lx) << 3)];
            #pragma unroll
            for (int t = 0; t < 4; ++t) {
                const bf16x8 vb = *(const bf16x8*)&Vt_s[((c2 * 4 + q4) << 9) + (t << 7) + (lx << 3)];
                Oacc[t] = __builtin_amdgcn_mfma_f32_16x16x32_bf16(pa, vb, Oacc[t], 0, 0, 0);
            }
            Lacc = __builtin_amdgcn_mfma_f32_16x16x32_bf16(pa, ones, Lacc, 0, 0, 0);
        }
        __syncthreads();   // all waves done reading K/Vt before next commit
    }

    // ---- epilogue: unnormalized fp32 partial + (m2, l); slot = per-bh idx ----
    const int slot = bh * CPB + idx;
    float* op = Opart + ((size_t)slot << 12);
    #pragma unroll
    for (int r = 0; r < 4; ++r) {
        const int row = w * 16 + q4 * 4 + r;
        #pragma unroll
        for (int t = 0; t < 4; ++t)
            op[row * 64 + t * 16 + lx] = Oacc[t][r];
        if (lx == 0) {
            Mp[slot * 64 + row] = m_st[r];   // log2 domain
            Lp[slot * 64 + row] = Lacc[r];
        }
    }
}

// ---------------------------------------------------------------------------
// Combine <=8 chunk partials per (bh, qt), log2-domain weights.
// ---------------------------------------------------------------------------
__global__ __launch_bounds__(256)
void attn_combine(const float* __restrict__ Opart, const float* __restrict__ Mp,
                  const float* __restrict__ Lp,
                  unsigned short* __restrict__ AOh, unsigned short* __restrict__ AOl)
{
    const int bh = blockIdx.x >> 5, qt = blockIdx.x & 31;
    const int g = qt >> 2, C = g + 1;
    const int first = 2 * g * (g + 1) + (qt & 3) * C;
    const int row = threadIdx.x >> 2, qd = threadIdx.x & 3;
    const int slot0 = bh * CPB + first;

    float m = -INFINITY;
    for (int c = 0; c < C; ++c) m = fmaxf(m, Mp[(slot0 + c) * 64 + row]);
    float L = 0.f;
    float o[16];
    #pragma unroll
    for (int j = 0; j < 16; ++j) o[j] = 0.f;

    for (int c = 0; c < C; ++c) {
        const float wgt = exp2f(Mp[(slot0 + c) * 64 + row] - m);
        L += wgt * Lp[(slot0 + c) * 64 + row];
        const float* op = Opart + (((size_t)(slot0 + c)) << 12) + row * 64 + qd * 16;
        #pragma unroll
        for (int j4 = 0; j4 < 4; ++j4) {
            float4 v = *(const float4*)(op + j4 * 4);
            o[j4*4+0] = fmaf(wgt, v.x, o[j4*4+0]);
            o[j4*4+1] = fmaf(wgt, v.y, o[j4*4+1]);
            o[j4*4+2] = fmaf(wgt, v.z, o[j4*4+2]);
            o[j4*4+3] = fmaf(wgt, v.w, o[j4*4+3]);
        }
    }

    const float inv = 1.f / L;
    const size_t obase = (((size_t)bh * NN + qt * 64 + row) << 6) + qd * 16;
    union { unsigned short u[8]; uint4 v; } h2[2], l2[2];
    #pragma unroll
    for (int j = 0; j < 16; ++j) {
        const float ov = o[j] * inv;
        const unsigned short h = f2bf(ov);
        const unsigned short l = f2bf(ov - bf2f(h));
        h2[j >> 3].u[j & 7] = h;
        l2[j >> 3].u[j & 7] = l;
    }
    *(uint4*)(AOh + obase)     = h2[0].v;
    *(uint4*)(AOh + obase + 8) = h2[1].v;
    *(uint4*)(AOl + obase)     = l2[0].v;
    *(uint4*)(AOl + obase + 8) = l2[1].v;
}

// ---------------------------------------------------------------------------
extern "C" void kernel_launch(void* const* d_in, const int* in_sizes, int n_in,
                              void* d_out, int out_size, void* d_ws, size_t ws_size,
                              hipStream_t stream)
{
    const float* x        = (const float*)d_in[0];
    const float* Wq       = (const float*)d_in[1];
    const float* Wk       = (const float*)d_in[2];
    const float* Wv       = (const float*)d_in[3];
    const float* Wo       = (const float*)d_in[4];
    const float* log_c    = (const float*)d_in[5];
    const float* log_beta = (const float*)d_in[6];
    float* out = (float*)d_out;

    unsigned short* p = (unsigned short*)d_ws;
    unsigned short* Qhi = p;            p += EE;
    unsigned short* Qlo = p;            p += EE;
    unsigned short* Khi = p;            p += EE;
    unsigned short* Klo = p;            p += EE;
    unsigned short* Vtr = p;            p += EE;
    unsigned short* AOh = p;            p += EE;
    unsigned short* AOl = p;            p += EE;
    float* QN    = (float*)p;
    float* KN    = QN + (size_t)BB * HH * NN;
    float* Opart = KN + (size_t)BB * HH * NN;                 // 2304 x 4096 fp32
    float* Mp    = Opart + (size_t)NSLOT * 64 * 64;
    float* Lp    = Mp + (size_t)NSLOT * 64;

    mm_mfma<128, true><<<dim3(MTOT / 64, DDIM / 128, 3), 256, 0, stream>>>(
        x, nullptr, nullptr, Wq, Wk, Wv,
        Qhi, Qlo, Khi, Klo, Vtr, nullptr, QN, KN);
    attn_mfma<<<dim3(CPB, 16), 256, 0, stream>>>(Qhi, Qlo, Khi, Klo, Vtr, QN, KN,
                                                 log_c, log_beta, Opart, Mp, Lp);
    attn_combine<<<dim3(512), 256, 0, stream>>>(Opart, Mp, Lp, AOh, AOl);
    mm_mfma<64, false><<<dim3(MTOT / 64, DDIM / 64, 1), 256, 0, stream>>>(
        nullptr, AOh, AOl, Wo, nullptr, nullptr,
        nullptr, nullptr, nullptr, nullptr, nullptr, out, nullptr, nullptr);
}

// Round 10
// 190.535 us; speedup vs baseline: 1.1547x; 1.0845x over previous
//
#include <hip/hip_runtime.h>
#include <math.h>

#define BB   2
#define NN   2048
#define DDIM 512
#define HH   8
#define DH   64
#define MTOT (BB*NN)      // 4096
#define EE   (BB*HH*NN*DH)   // 2,097,152 elems per Q/K/V-like array
#define CPB  144             // chunk-blocks per bh (sum over qt of ceil((qt+1)/4))
#define NSLOT (BB*HH*CPB)    // 2304 partial slots

typedef __attribute__((ext_vector_type(8))) short bf16x8;   // 8 bf16 = 4 VGPRs
typedef __attribute__((ext_vector_type(4))) float f32x4;

__device__ __forceinline__ float softplus_f(float x) {
    return x > 20.f ? x : log1pf(expf(x));
}
__device__ __forceinline__ unsigned short f2bf(float x) {   // round-to-nearest-even
    union { float f; unsigned u; } v; v.f = x;
    unsigned r = v.u + 0x7fffu + ((v.u >> 16) & 1u);
    return (unsigned short)(r >> 16);
}
__device__ __forceinline__ float bf2f(unsigned short h) {
    union { unsigned u; float f; } v; v.u = ((unsigned)h) << 16; return v.f;
}
__device__ __forceinline__ void split4(float4 v, ushort4& h, ushort4& l) {
    h.x = f2bf(v.x); l.x = f2bf(v.x - bf2f(h.x));
    h.y = f2bf(v.y); l.y = f2bf(v.y - bf2f(h.y));
    h.z = f2bf(v.z); l.z = f2bf(v.z - bf2f(h.z));
    h.w = f2bf(v.w); l.w = f2bf(v.w - bf2f(h.w));
}

// ---------------------------------------------------------------------------
// Q/K/V projection GEMM, hi/lo-compensated bf16, on-the-fly fp32 split.
// 64x128 tile, BK=32. Epilogue: Q/K hi+lo [B,H,N,dh] + fused norms, or Vt
// directly transposed [B,H,64,N].
// ---------------------------------------------------------------------------
__global__ __launch_bounds__(256, 3)
void mm_proj(const float* __restrict__ Xf,
             const float* __restrict__ W0, const float* __restrict__ W1,
             const float* __restrict__ W2,
             unsigned short* __restrict__ Qhi, unsigned short* __restrict__ Qlo,
             unsigned short* __restrict__ Khi, unsigned short* __restrict__ Klo,
             unsigned short* __restrict__ Vt,
             float* __restrict__ QN, float* __restrict__ KN)
{
    const int mode = blockIdx.z;
    const float* W = (mode == 1) ? W1 : ((mode == 2) ? W2 : W0);
    const int m0 = blockIdx.x * 64, n0 = blockIdx.y * 128;

    __shared__ unsigned short Ah_s[4 * 64 * 8];    // [kq][64][8]
    __shared__ unsigned short Al_s[4 * 64 * 8];
    __shared__ unsigned short Bh_s[4 * 128 * 8];   // [kq][128][8]
    __shared__ unsigned short Bl_s[4 * 128 * 8];

    const int tid  = threadIdx.x;
    const int lane = tid & 63, lx = lane & 15, q4 = lane >> 4;
    const int w = tid >> 6, wm = w & 1, wn = w >> 1;
    const int rowA = tid & 63, kqA = tid >> 6;
    const int rowB = tid & 127, kbB = tid >> 7;

    f32x4 acc[2][4];
    #pragma unroll
    for (int mt = 0; mt < 2; ++mt)
        #pragma unroll
        for (int nt = 0; nt < 4; ++nt)
            acc[mt][nt] = (f32x4){0.f, 0.f, 0.f, 0.f};

    const int am = m0 + rowA;
    const size_t brow = (size_t)(n0 + rowB) * DDIM;

    float4 fa0, fa1, fb0, fb1, fb2, fb3;
    {
        const float* ap = Xf + (size_t)am * DDIM + kqA * 8;
        fa0 = *(const float4*)(ap);
        fa1 = *(const float4*)(ap + 4);
        const int eb = kbB * 8;
        fb0 = *(const float4*)(W + brow + eb);
        fb1 = *(const float4*)(W + brow + eb + 4);
        fb2 = *(const float4*)(W + brow + eb + 16);
        fb3 = *(const float4*)(W + brow + eb + 20);
    }

    for (int k0 = 0; k0 < DDIM; k0 += 32) {
        __syncthreads();
        {
            ushort4 h0, l0, h1, l1;
            split4(fa0, h0, l0); split4(fa1, h1, l1);
            const int off = (kqA << 9) + (rowA << 3);
            *(ushort4*)&Ah_s[off]     = h0;  *(ushort4*)&Ah_s[off + 4] = h1;
            *(ushort4*)&Al_s[off]     = l0;  *(ushort4*)&Al_s[off + 4] = l1;
            split4(fb0, h0, l0); split4(fb1, h1, l1);
            const int offb = (kbB << 10) + (rowB << 3);
            *(ushort4*)&Bh_s[offb]     = h0;  *(ushort4*)&Bh_s[offb + 4] = h1;
            *(ushort4*)&Bl_s[offb]     = l0;  *(ushort4*)&Bl_s[offb + 4] = l1;
            split4(fb2, h0, l0); split4(fb3, h1, l1);
            const int offb2 = ((kbB + 2) << 10) + (rowB << 3);
            *(ushort4*)&Bh_s[offb2]     = h0;  *(ushort4*)&Bh_s[offb2 + 4] = h1;
            *(ushort4*)&Bl_s[offb2]     = l0;  *(ushort4*)&Bl_s[offb2 + 4] = l1;
        }
        __syncthreads();

        if (k0 + 32 < DDIM) {
            const float* ap = Xf + (size_t)am * DDIM + k0 + 32 + kqA * 8;
            fa0 = *(const float4*)(ap);
            fa1 = *(const float4*)(ap + 4);
            const int eb = k0 + 32 + kbB * 8;
            fb0 = *(const float4*)(W + brow + eb);
            fb1 = *(const float4*)(W + brow + eb + 4);
            fb2 = *(const float4*)(W + brow + eb + 16);
            fb3 = *(const float4*)(W + brow + eb + 20);
        }

        bf16x8 fah[2], fal[2], fbh[4], fbl[4];
        #pragma unroll
        for (int mt = 0; mt < 2; ++mt) {
            const int off = (q4 << 9) + ((wm * 32 + mt * 16 + lx) << 3);
            fah[mt] = *(const bf16x8*)&Ah_s[off];
            fal[mt] = *(const bf16x8*)&Al_s[off];
        }
        #pragma unroll
        for (int nt = 0; nt < 4; ++nt) {
            const int off = (q4 << 10) + ((wn * 64 + nt * 16 + lx) << 3);
            fbh[nt] = *(const bf16x8*)&Bh_s[off];
            fbl[nt] = *(const bf16x8*)&Bl_s[off];
        }
        #pragma unroll
        for (int mt = 0; mt < 2; ++mt)
            #pragma unroll
            for (int nt = 0; nt < 4; ++nt) {
                acc[mt][nt] = __builtin_amdgcn_mfma_f32_16x16x32_bf16(fah[mt], fbh[nt], acc[mt][nt], 0, 0, 0);
                acc[mt][nt] = __builtin_amdgcn_mfma_f32_16x16x32_bf16(fah[mt], fbl[nt], acc[mt][nt], 0, 0, 0);
                acc[mt][nt] = __builtin_amdgcn_mfma_f32_16x16x32_bf16(fal[mt], fbh[nt], acc[mt][nt], 0, 0, 0);
            }
    }

    // ---- fused row norms (modes 0/1; wave's wn-half spans one head) ----
    if (mode == 0 || mode == 1) {
        float* Np = (mode == 0) ? QN : KN;
        const int head = (n0 + wn * 64) >> 6;
        #pragma unroll
        for (int mt = 0; mt < 2; ++mt)
            #pragma unroll
            for (int r = 0; r < 4; ++r) {
                float s = 0.f;
                #pragma unroll
                for (int nt = 0; nt < 4; ++nt) s = fmaf(acc[mt][nt][r], acc[mt][nt][r], s);
                s += __shfl_xor(s, 1);
                s += __shfl_xor(s, 2);
                s += __shfl_xor(s, 4);
                s += __shfl_xor(s, 8);
                if (lx == 0) {
                    const int m = m0 + wm * 32 + mt * 16 + q4 * 4 + r;
                    Np[(size_t)((m >> 11) * HH + head) * NN + (m & 2047)] = s;
                }
            }
    }

    // ---- epilogue (C row m = q4*4+reg, col j = lx) ----
    if (mode == 2) {
        #pragma unroll
        for (int mt = 0; mt < 2; ++mt) {
            const int mb = m0 + wm * 32 + mt * 16 + q4 * 4;
            const int b = mb >> 11, nb = mb & 2047;
            #pragma unroll
            for (int nt = 0; nt < 4; ++nt) {
                const int j = n0 + wn * 64 + nt * 16 + lx;
                ushort4 pv = make_ushort4(f2bf(acc[mt][nt][0]), f2bf(acc[mt][nt][1]),
                                          f2bf(acc[mt][nt][2]), f2bf(acc[mt][nt][3]));
                *(ushort4*)(Vt + ((size_t)(b * HH + (j >> 6)) * 64 + (j & 63)) * NN + nb) = pv;
            }
        }
    } else {
        #pragma unroll
        for (int mt = 0; mt < 2; ++mt) {
            #pragma unroll
            for (int r = 0; r < 4; ++r) {
                const int m = m0 + wm * 32 + mt * 16 + q4 * 4 + r;
                const int b = m >> 11, n2 = m & 2047;
                #pragma unroll
                for (int nt = 0; nt < 4; ++nt) {
                    const int j = n0 + wn * 64 + nt * 16 + lx;
                    const float v = acc[mt][nt][r];
                    const size_t idx = (((size_t)(b * HH + (j >> 6)) * NN + n2) << 6) + (j & 63);
                    const unsigned short h = f2bf(v);
                    const unsigned short l = f2bf(v - bf2f(h));
                    if (mode == 0) { Qhi[idx] = h; Qlo[idx] = l; }
                    else           { Khi[idx] = h; Klo[idx] = l; }
                }
            }
        }
    }
}

// ---------------------------------------------------------------------------
// Output projection, PLAIN bf16 (error budget allows): out = AO @ Wo^T.
// A = AO bf16 (BHND gather), B = Wo fp32 -> bf16 on the fly. 1 MFMA/tile.
// ---------------------------------------------------------------------------
__global__ __launch_bounds__(256, 4)
void mm_out(const unsigned short* __restrict__ AO, const float* __restrict__ Wo,
            float* __restrict__ Outp)
{
    const int m0 = blockIdx.x * 64, n0 = blockIdx.y * 64;

    __shared__ unsigned short Ah_s[4 * 64 * 8];    // [kq][64][8]
    __shared__ unsigned short Bh_s[4 * 64 * 8];

    const int tid  = threadIdx.x;
    const int lane = tid & 63, lx = lane & 15, q4 = lane >> 4;
    const int w = tid >> 6, wm = w & 1, wn = w >> 1;
    const int rowA = tid & 63, kqA = tid >> 6;

    f32x4 acc[2][2];
    #pragma unroll
    for (int mt = 0; mt < 2; ++mt)
        #pragma unroll
        for (int nt = 0; nt < 2; ++nt)
            acc[mt][nt] = (f32x4){0.f, 0.f, 0.f, 0.f};

    const int am = m0 + rowA;
    const int ab = am >> 11, an = am & 2047;
    const size_t brow = (size_t)(n0 + rowA) * DDIM;

    uint4 rah; float4 fb0, fb1;
    {
        const int e = kqA * 8;
        rah = *(const uint4*)(AO + (((size_t)(ab * HH + (e >> 6)) * NN + an) << 6) + (e & 63));
        fb0 = *(const float4*)(Wo + brow + e);
        fb1 = *(const float4*)(Wo + brow + e + 4);
    }

    for (int k0 = 0; k0 < DDIM; k0 += 32) {
        __syncthreads();
        {
            const int off = (kqA << 9) + (rowA << 3);
            *(uint4*)&Ah_s[off] = rah;
            ushort4 h0 = make_ushort4(f2bf(fb0.x), f2bf(fb0.y), f2bf(fb0.z), f2bf(fb0.w));
            ushort4 h1 = make_ushort4(f2bf(fb1.x), f2bf(fb1.y), f2bf(fb1.z), f2bf(fb1.w));
            *(ushort4*)&Bh_s[off]     = h0;
            *(ushort4*)&Bh_s[off + 4] = h1;
        }
        __syncthreads();

        if (k0 + 32 < DDIM) {
            const int e = k0 + 32 + kqA * 8;
            rah = *(const uint4*)(AO + (((size_t)(ab * HH + (e >> 6)) * NN + an) << 6) + (e & 63));
            fb0 = *(const float4*)(Wo + brow + e);
            fb1 = *(const float4*)(Wo + brow + e + 4);
        }

        bf16x8 fah[2], fbh[2];
        #pragma unroll
        for (int mt = 0; mt < 2; ++mt)
            fah[mt] = *(const bf16x8*)&Ah_s[(q4 << 9) + ((wm * 32 + mt * 16 + lx) << 3)];
        #pragma unroll
        for (int nt = 0; nt < 2; ++nt)
            fbh[nt] = *(const bf16x8*)&Bh_s[(q4 << 9) + ((wn * 32 + nt * 16 + lx) << 3)];
        #pragma unroll
        for (int mt = 0; mt < 2; ++mt)
            #pragma unroll
            for (int nt = 0; nt < 2; ++nt)
                acc[mt][nt] = __builtin_amdgcn_mfma_f32_16x16x32_bf16(fah[mt], fbh[nt], acc[mt][nt], 0, 0, 0);
    }

    #pragma unroll
    for (int mt = 0; mt < 2; ++mt)
        #pragma unroll
        for (int r = 0; r < 4; ++r) {
            const int m = m0 + wm * 32 + mt * 16 + q4 * 4 + r;
            #pragma unroll
            for (int nt = 0; nt < 2; ++nt)
                Outp[(size_t)m * DDIM + n0 + wn * 32 + nt * 16 + lx] = acc[mt][nt][r];
        }
}

// ---------------------------------------------------------------------------
// MFMA flash attention, split-K, S^T FORMULATION: S^T = K·Q^T (operand swap,
// same fragments). C-layout gives qrow = lane&15 -> per-thread SCALAR softmax
// state, 4-shfl reductions (was 16), P written as 4 ds_write_b64 (was 16 b16),
// epilogue as 4 float4 stores.
// ---------------------------------------------------------------------------
__global__ __launch_bounds__(256, 4)
void attn_mfma(const unsigned short* __restrict__ Qhi, const unsigned short* __restrict__ Qlo,
               const unsigned short* __restrict__ Khi, const unsigned short* __restrict__ Klo,
               const unsigned short* __restrict__ Vt,
               const float* __restrict__ QN, const float* __restrict__ KN,
               const float* __restrict__ pLC, const float* __restrict__ pLB,
               float* __restrict__ Opart, float* __restrict__ Mp, float* __restrict__ Lp)
{
    __shared__ unsigned short Kh_s[8 * 64 * 8];   // [dchunk][key][8]
    __shared__ unsigned short Kl_s[8 * 64 * 8];
    __shared__ unsigned short Vt_s[8 * 64 * 8];   // [keychunk][d][8]
    __shared__ unsigned short P_s [8 * 64 * 8];   // [keychunk][qrow][8]
    __shared__ __align__(16) float kn_s[64];
    __shared__ float qn_s[64];

    // decode (qt, chunk): group g = qt>>2 has C=g+1 chunks/qt, base 2g(g+1)
    const int idx = blockIdx.x;
    const int g   = (idx >= 112) ? 7 : (idx >= 84) ? 6 : (idx >= 60) ? 5 :
                    (idx >= 40) ? 4 : (idx >= 24) ? 3 : (idx >= 12) ? 2 :
                    (idx >= 4)  ? 1 : 0;
    const int rem = idx - 2 * g * (g + 1);
    const int C   = g + 1;
    const int qt  = g * 4 + rem / C;
    const int c0  = rem % C;
    const int bh  = blockIdx.y;
    const int nk  = qt + 1;
    const int kt0  = (c0 * nk) / C;        // balanced ranges (len 2..4)
    const int kend = ((c0 + 1) * nk) / C;

    const int tid  = threadIdx.x;
    const int w    = tid >> 6;
    const int lane = tid & 63;
    const int lx   = lane & 15;
    const int q4   = lane >> 4;
    const int qrl  = w * 16 + lx;          // this thread's (single) local q-row

    const float hc    = softplus_f(pLC[0]);
    const float betaL = (softplus_f(pLB[0]) + 0.5f) * 1.44269504f;  // log2 domain

    const size_t base = ((size_t)bh * NN) << 6;

    // Q fragments (lane holds row qt*64+qrl, k-chunk q4*8) — serve as B operand
    const unsigned short* qrh = Qhi + base + ((size_t)(qt * 64 + qrl) << 6) + q4 * 8;
    const unsigned short* qrl_p = Qlo + base + ((size_t)(qt * 64 + qrl) << 6) + q4 * 8;
    const bf16x8 qh0 = *(const bf16x8*)(qrh);
    const bf16x8 qh1 = *(const bf16x8*)(qrh + 32);
    const bf16x8 ql0 = *(const bf16x8*)(qrl_p);
    const bf16x8 ql1 = *(const bf16x8*)(qrl_p + 32);

    if (tid < 64) qn_s[tid] = QN[(size_t)bh * NN + qt * 64 + tid];

    f32x4 Oacc[4];     // O^T: d = t2*16+q4*4+r, qrow = qrl
    #pragma unroll
    for (int t = 0; t < 4; ++t) Oacc[t] = (f32x4){0.f, 0.f, 0.f, 0.f};
    float m_st = -INFINITY, l_st = 0.f;

    const int sc = tid >> 6, sr = tid & 63;

    // prefetch first tile (kt0)
    uint4 pKh0, pKh1, pKl0, pKl1, pVt0, pVt1; float pkn = 0.f;
    {
        const unsigned short* kh = Khi + base + ((size_t)(kt0 * 64 + sr) << 6) + sc * 8;
        const unsigned short* kl = Klo + base + ((size_t)(kt0 * 64 + sr) << 6) + sc * 8;
        const unsigned short* vt = Vt  + base + (size_t)sr * NN + kt0 * 64 + sc * 8;
        pKh0 = *(const uint4*)(kh);  pKh1 = *(const uint4*)(kh + 32);
        pKl0 = *(const uint4*)(kl);  pKl1 = *(const uint4*)(kl + 32);
        pVt0 = *(const uint4*)(vt);  pVt1 = *(const uint4*)(vt + 32);
        if (tid < 64) pkn = KN[(size_t)bh * NN + kt0 * 64 + tid];
    }

    __syncthreads();   // qn_s visible
    const float qn = qn_s[qrl];

    for (int kt = kt0; kt < kend; ++kt) {
        // ---- commit prefetched tile (lane-contiguous, conflict-free) ----
        const int soff = (sc << 9) + (sr << 3);
        *(uint4*)&Kh_s[soff]            = pKh0;
        *(uint4*)&Kh_s[soff + (4 << 9)] = pKh1;
        *(uint4*)&Kl_s[soff]            = pKl0;
        *(uint4*)&Kl_s[soff + (4 << 9)] = pKl1;
        *(uint4*)&Vt_s[soff]            = pVt0;
        *(uint4*)&Vt_s[soff + (4 << 9)] = pVt1;
        if (tid < 64) kn_s[tid] = pkn;
        __syncthreads();

        // ---- prefetch tile kt+1 ----
        if (kt + 1 < kend) {
            const unsigned short* kh = Khi + base + ((size_t)((kt + 1) * 64 + sr) << 6) + sc * 8;
            const unsigned short* kl = Klo + base + ((size_t)((kt + 1) * 64 + sr) << 6) + sc * 8;
            const unsigned short* vt = Vt  + base + (size_t)sr * NN + (kt + 1) * 64 + sc * 8;
            pKh0 = *(const uint4*)(kh);  pKh1 = *(const uint4*)(kh + 32);
            pKl0 = *(const uint4*)(kl);  pKl1 = *(const uint4*)(kl + 32);
            pVt0 = *(const uint4*)(vt);  pVt1 = *(const uint4*)(vt + 32);
            if (tid < 64) pkn = KN[(size_t)bh * NN + (kt + 1) * 64 + tid];
        }

        // ---- S^T = K Q^T (hi/lo compensated): A = K rows, B = Q rows ----
        f32x4 S[4];    // S[t][r]: key = t*16 + q4*4 + r, qrow = qrl
        #pragma unroll
        for (int t = 0; t < 4; ++t) {
            f32x4 acc = (f32x4){0.f, 0.f, 0.f, 0.f};
            #pragma unroll
            for (int c2 = 0; c2 < 2; ++c2) {
                const int off = ((c2 * 4 + q4) << 9) + ((t * 16 + lx) << 3);
                const bf16x8 kh = *(const bf16x8*)&Kh_s[off];
                const bf16x8 kl = *(const bf16x8*)&Kl_s[off];
                const bf16x8 qh = c2 ? qh1 : qh0;
                const bf16x8 ql = c2 ? ql1 : ql0;
                acc = __builtin_amdgcn_mfma_f32_16x16x32_bf16(kh, qh, acc, 0, 0, 0);
                acc = __builtin_amdgcn_mfma_f32_16x16x32_bf16(kh, ql, acc, 0, 0, 0);
                acc = __builtin_amdgcn_mfma_f32_16x16x32_bf16(kl, qh, acc, 0, 0, 0);
            }
            S[t] = acc;
        }

        // ---- hyperbolic distance -> log2-scores (all 16 share qrow qrl) ----
        const bool diag = (kt == qt);
        float mloc = -INFINITY;
        #pragma unroll
        for (int t = 0; t < 4; ++t) {
            float kn4[4];
            *(float4*)kn4 = *(const float4*)&kn_s[t * 16 + q4 * 4];
            #pragma unroll
            for (int r = 0; r < 4; ++r) {
                const float sumn = qn + kn4[r];
                float diff = fmaxf(fmaf(-2.f, S[t][r], sumn), 0.f);
                float s = -betaL * sqrtf(fmaf(hc, sumn, 1.f) * (diff + 1e-8f));
                if (diag && (t * 16 + q4 * 4 + r) > qrl) s = -INFINITY;
                S[t][r] = s;
                mloc = fmaxf(mloc, s);
            }
        }
        mloc = fmaxf(mloc, __shfl_xor(mloc, 16));
        mloc = fmaxf(mloc, __shfl_xor(mloc, 32));
        const float mn = fmaxf(m_st, mloc);
        const float al = exp2f(m_st - mn);
        m_st = mn;

        float rs = 0.f;
        #pragma unroll
        for (int t = 0; t < 4; ++t) {
            const float p0 = exp2f(S[t][0] - mn);
            const float p1 = exp2f(S[t][1] - mn);
            const float p2 = exp2f(S[t][2] - mn);
            const float p3 = exp2f(S[t][3] - mn);
            rs += (p0 + p1) + (p2 + p3);
            // keys t*16+q4*4+{0..3} are LDS-consecutive -> one b64 store
            ushort4 pk = make_ushort4(f2bf(p0), f2bf(p1), f2bf(p2), f2bf(p3));
            *(ushort4*)&P_s[((2 * t + (q4 >> 1)) << 9) + (qrl << 3) + ((q4 & 1) << 2)] = pk;
        }
        rs += __shfl_xor(rs, 16);
        rs += __shfl_xor(rs, 32);
        l_st = l_st * al + rs;
        #pragma unroll
        for (int t = 0; t < 4; ++t) {
            Oacc[t][0] *= al; Oacc[t][1] *= al;
            Oacc[t][2] *= al; Oacc[t][3] *= al;
        }

        // P_s rows qrl are wave-local; same-wave DS ops pipe-ordered.
        __builtin_amdgcn_wave_barrier();

        // ---- O^T += V^T P : A = Vt rows (d), B = P (qrow cols) ----
        #pragma unroll
        for (int c2 = 0; c2 < 2; ++c2) {
            const bf16x8 pb = *(const bf16x8*)&P_s[((c2 * 4 + q4) << 9) + (qrl << 3)];
            #pragma unroll
            for (int t2 = 0; t2 < 4; ++t2) {
                const bf16x8 va = *(const bf16x8*)&Vt_s[((c2 * 4 + q4) << 9) + ((t2 * 16 + lx) << 3)];
                Oacc[t2] = __builtin_amdgcn_mfma_f32_16x16x32_bf16(va, pb, Oacc[t2], 0, 0, 0);
            }
        }
        __syncthreads();   // all waves done reading K/Vt/P before next commit
    }

    // ---- epilogue: partial [qrow][d] fp32 + (m2, l); slot = per-bh idx ----
    const int slot = bh * CPB + idx;
    float* op = Opart + ((size_t)slot << 12);
    #pragma unroll
    for (int t2 = 0; t2 < 4; ++t2)
        *(f32x4*)&op[qrl * 64 + t2 * 16 + q4 * 4] = Oacc[t2];
    if (q4 == 0) {
        Mp[slot * 64 + qrl] = m_st;   // log2 domain
        Lp[slot * 64 + qrl] = l_st;
    }
}

// ---------------------------------------------------------------------------
// Combine <=8 chunk partials per (bh, qt), log2-domain weights; emits AO bf16.
// ---------------------------------------------------------------------------
__global__ __launch_bounds__(256)
void attn_combine(const float* __restrict__ Opart, const float* __restrict__ Mp,
                  const float* __restrict__ Lp, unsigned short* __restrict__ AO)
{
    const int bh = blockIdx.x >> 5, qt = blockIdx.x & 31;
    const int g = qt >> 2, C = g + 1;
    const int first = 2 * g * (g + 1) + (qt & 3) * C;
    const int row = threadIdx.x >> 2, qd = threadIdx.x & 3;
    const int slot0 = bh * CPB + first;

    float m = -INFINITY;
    for (int c = 0; c < C; ++c) m = fmaxf(m, Mp[(slot0 + c) * 64 + row]);
    float L = 0.f;
    float o[16];
    #pragma unroll
    for (int j = 0; j < 16; ++j) o[j] = 0.f;

    for (int c = 0; c < C; ++c) {
        const float wgt = exp2f(Mp[(slot0 + c) * 64 + row] - m);
        L += wgt * Lp[(slot0 + c) * 64 + row];
        const float* op = Opart + (((size_t)(slot0 + c)) << 12) + row * 64 + qd * 16;
        #pragma unroll
        for (int j4 = 0; j4 < 4; ++j4) {
            float4 v = *(const float4*)(op + j4 * 4);
            o[j4*4+0] = fmaf(wgt, v.x, o[j4*4+0]);
            o[j4*4+1] = fmaf(wgt, v.y, o[j4*4+1]);
            o[j4*4+2] = fmaf(wgt, v.z, o[j4*4+2]);
            o[j4*4+3] = fmaf(wgt, v.w, o[j4*4+3]);
        }
    }

    const float inv = 1.f / L;
    const size_t obase = (((size_t)bh * NN + qt * 64 + row) << 6) + qd * 16;
    union { unsigned short u[8]; uint4 v; } h2[2];
    #pragma unroll
    for (int j = 0; j < 16; ++j)
        h2[j >> 3].u[j & 7] = f2bf(o[j] * inv);
    *(uint4*)(AO + obase)     = h2[0].v;
    *(uint4*)(AO + obase + 8) = h2[1].v;
}

// ---------------------------------------------------------------------------
extern "C" void kernel_launch(void* const* d_in, const int* in_sizes, int n_in,
                              void* d_out, int out_size, void* d_ws, size_t ws_size,
                              hipStream_t stream)
{
    const float* x        = (const float*)d_in[0];
    const float* Wq       = (const float*)d_in[1];
    const float* Wk       = (const float*)d_in[2];
    const float* Wv       = (const float*)d_in[3];
    const float* Wo       = (const float*)d_in[4];
    const float* log_c    = (const float*)d_in[5];
    const float* log_beta = (const float*)d_in[6];
    float* out = (float*)d_out;

    unsigned short* p = (unsigned short*)d_ws;
    unsigned short* Qhi = p;            p += EE;
    unsigned short* Qlo = p;            p += EE;
    unsigned short* Khi = p;            p += EE;
    unsigned short* Klo = p;            p += EE;
    unsigned short* Vtr = p;            p += EE;
    unsigned short* AO  = p;            p += EE;
    float* QN    = (float*)p;
    float* KN    = QN + (size_t)BB * HH * NN;
    float* Opart = KN + (size_t)BB * HH * NN;                 // 2304 x 4096 fp32
    float* Mp    = Opart + (size_t)NSLOT * 64 * 64;
    float* Lp    = Mp + (size_t)NSLOT * 64;

    mm_proj<<<dim3(MTOT / 64, DDIM / 128, 3), 256, 0, stream>>>(
        x, Wq, Wk, Wv, Qhi, Qlo, Khi, Klo, Vtr, QN, KN);
    attn_mfma<<<dim3(CPB, 16), 256, 0, stream>>>(Qhi, Qlo, Khi, Klo, Vtr, QN, KN,
                                                 log_c, log_beta, Opart, Mp, Lp);
    attn_combine<<<dim3(512), 256, 0, stream>>>(Opart, Mp, Lp, AO);
    mm_out<<<dim3(MTOT / 64, DDIM / 64), 256, 0, stream>>>(AO, Wo, out);
}

// Round 11
// 183.297 us; speedup vs baseline: 1.2002x; 1.0395x over previous
//
#include <hip/hip_runtime.h>
#include <hip/hip_bf16.h>
#include <math.h>

#define BB   2
#define NN   2048
#define DDIM 512
#define HH   8
#define DH   64
#define MTOT (BB*NN)      // 4096
#define EE   (BB*HH*NN*DH)   // 2,097,152 elems per Q/K/V-like array
#define WN   (DDIM*DDIM)     // 262,144 elems per weight
#define CPB  144             // chunk-blocks per bh (sum over qt of ceil((qt+1)/4))
#define NSLOT (BB*HH*CPB)    // 2304 partial slots

typedef __attribute__((ext_vector_type(8))) short bf16x8;   // 8 bf16 = 4 VGPRs
typedef __attribute__((ext_vector_type(4))) float f32x4;

__device__ __forceinline__ float softplus_f(float x) {
    return x > 20.f ? x : log1pf(expf(x));
}
__device__ __forceinline__ unsigned short f2bf(float x) {   // round-to-nearest-even
    union { float f; unsigned u; } v; v.f = x;
    unsigned r = v.u + 0x7fffu + ((v.u >> 16) & 1u);
    return (unsigned short)(r >> 16);
}
__device__ __forceinline__ float bf2f(unsigned short h) {
    union { unsigned u; float f; } v; v.u = ((unsigned)h) << 16; return v.f;
}
__device__ __forceinline__ void split4(float4 v, ushort4& h, ushort4& l) {
    h.x = f2bf(v.x); l.x = f2bf(v.x - bf2f(h.x));
    h.y = f2bf(v.y); l.y = f2bf(v.y - bf2f(h.y));
    h.z = f2bf(v.z); l.z = f2bf(v.z - bf2f(h.z));
    h.w = f2bf(v.w); l.w = f2bf(v.w - bf2f(h.w));
}
__device__ __forceinline__ ushort4 pk4(float a, float b, float c, float d) {
    union { __hip_bfloat162 b2[2]; ushort4 u4; } u;
    u.b2[0] = __float22bfloat162_rn(make_float2(a, b));   // v_cvt_pk_bf16_f32
    u.b2[1] = __float22bfloat162_rn(make_float2(c, d));
    return u.u4;
}

// ---------------------------------------------------------------------------
// W pre-split: Wq/Wk/Wv -> bf16 hi+lo (done ONCE; round-10 re-split W in every
// mm_proj block = 64x redundant VALU). Wo -> plain bf16.
// ---------------------------------------------------------------------------
__global__ __launch_bounds__(256)
void split_w(const float* __restrict__ Wq, const float* __restrict__ Wk,
             const float* __restrict__ Wv, const float* __restrict__ Wo,
             unsigned short* __restrict__ Whi, unsigned short* __restrict__ Wlo,
             unsigned short* __restrict__ Wob)
{
    const int i = blockIdx.x * 256 + threadIdx.x;   // one float4 per thread
    const int y = blockIdx.y;
    if (y < 3) {
        const float* src = (y == 0) ? Wq : ((y == 1) ? Wk : Wv);
        float4 v = *(const float4*)(src + 4 * (size_t)i);
        ushort4 h, l;
        split4(v, h, l);
        *(ushort4*)(Whi + (size_t)y * WN + 4 * (size_t)i) = h;
        *(ushort4*)(Wlo + (size_t)y * WN + 4 * (size_t)i) = l;
    } else {
        float4 v = *(const float4*)(Wo + 4 * (size_t)i);
        *(ushort4*)(Wob + 4 * (size_t)i) = pk4(v.x, v.y, v.z, v.w);
    }
}

// ---------------------------------------------------------------------------
// Q/K/V projection GEMM. A = x fp32 (split on the fly), B = pre-split W bf16.
// Modes 0/1 (Q,K): hi/lo compensated (3 MFMA) + fused norms. Mode 2 (V):
// PLAIN bf16 (1 MFMA — V is stored bf16 anyway), Vt written transposed.
// ---------------------------------------------------------------------------
__global__ __launch_bounds__(256, 3)
void mm_proj(const float* __restrict__ Xf,
             const unsigned short* __restrict__ Whi, const unsigned short* __restrict__ Wlo,
             unsigned short* __restrict__ Qhi, unsigned short* __restrict__ Qlo,
             unsigned short* __restrict__ Khi, unsigned short* __restrict__ Klo,
             unsigned short* __restrict__ Vt,
             float* __restrict__ QN, float* __restrict__ KN)
{
    const int mode = blockIdx.z;
    const unsigned short* Wh = Whi + (size_t)mode * WN;
    const unsigned short* Wl = Wlo + (size_t)mode * WN;
    const int m0 = blockIdx.x * 64, n0 = blockIdx.y * 128;

    __shared__ unsigned short Ah_s[4 * 64 * 8];    // [kq][64][8]
    __shared__ unsigned short Al_s[4 * 64 * 8];
    __shared__ unsigned short Bh_s[4 * 128 * 8];   // [kq][128][8]
    __shared__ unsigned short Bl_s[4 * 128 * 8];

    const int tid  = threadIdx.x;
    const int lane = tid & 63, lx = lane & 15, q4 = lane >> 4;
    const int w = tid >> 6, wm = w & 1, wn = w >> 1;
    const int rowA = tid & 63, kqA = tid >> 6;
    const int rowB = tid & 127, kbB = tid >> 7;

    f32x4 acc[2][4];
    #pragma unroll
    for (int mt = 0; mt < 2; ++mt)
        #pragma unroll
        for (int nt = 0; nt < 4; ++nt)
            acc[mt][nt] = (f32x4){0.f, 0.f, 0.f, 0.f};

    const int am = m0 + rowA;
    const size_t brow = (size_t)(n0 + rowB) * DDIM;

    float4 fa0, fa1;
    uint4 rbh0, rbh1, rbl0, rbl1;
    {
        const float* ap = Xf + (size_t)am * DDIM + kqA * 8;
        fa0 = *(const float4*)(ap);
        fa1 = *(const float4*)(ap + 4);
        const int eb = kbB * 8;
        rbh0 = *(const uint4*)(Wh + brow + eb);
        rbh1 = *(const uint4*)(Wh + brow + eb + 16);
        if (mode != 2) {
            rbl0 = *(const uint4*)(Wl + brow + eb);
            rbl1 = *(const uint4*)(Wl + brow + eb + 16);
        }
    }

    for (int k0 = 0; k0 < DDIM; k0 += 32) {
        __syncthreads();
        {
            ushort4 h0, l0, h1, l1;
            split4(fa0, h0, l0); split4(fa1, h1, l1);
            const int off = (kqA << 9) + (rowA << 3);
            *(ushort4*)&Ah_s[off]     = h0;  *(ushort4*)&Ah_s[off + 4] = h1;
            if (mode != 2) {
                *(ushort4*)&Al_s[off]     = l0;  *(ushort4*)&Al_s[off + 4] = l1;
            }
            const int offb  = (kbB << 10) + (rowB << 3);
            const int offb2 = ((kbB + 2) << 10) + (rowB << 3);
            *(uint4*)&Bh_s[offb]  = rbh0;
            *(uint4*)&Bh_s[offb2] = rbh1;
            if (mode != 2) {
                *(uint4*)&Bl_s[offb]  = rbl0;
                *(uint4*)&Bl_s[offb2] = rbl1;
            }
        }
        __syncthreads();

        if (k0 + 32 < DDIM) {
            const float* ap = Xf + (size_t)am * DDIM + k0 + 32 + kqA * 8;
            fa0 = *(const float4*)(ap);
            fa1 = *(const float4*)(ap + 4);
            const int eb = k0 + 32 + kbB * 8;
            rbh0 = *(const uint4*)(Wh + brow + eb);
            rbh1 = *(const uint4*)(Wh + brow + eb + 16);
            if (mode != 2) {
                rbl0 = *(const uint4*)(Wl + brow + eb);
                rbl1 = *(const uint4*)(Wl + brow + eb + 16);
            }
        }

        bf16x8 fah[2], fal[2], fbh[4], fbl[4];
        #pragma unroll
        for (int mt = 0; mt < 2; ++mt) {
            const int off = (q4 << 9) + ((wm * 32 + mt * 16 + lx) << 3);
            fah[mt] = *(const bf16x8*)&Ah_s[off];
            if (mode != 2) fal[mt] = *(const bf16x8*)&Al_s[off];
        }
        #pragma unroll
        for (int nt = 0; nt < 4; ++nt) {
            const int off = (q4 << 10) + ((wn * 64 + nt * 16 + lx) << 3);
            fbh[nt] = *(const bf16x8*)&Bh_s[off];
            if (mode != 2) fbl[nt] = *(const bf16x8*)&Bl_s[off];
        }
        #pragma unroll
        for (int mt = 0; mt < 2; ++mt)
            #pragma unroll
            for (int nt = 0; nt < 4; ++nt) {
                acc[mt][nt] = __builtin_amdgcn_mfma_f32_16x16x32_bf16(fah[mt], fbh[nt], acc[mt][nt], 0, 0, 0);
                if (mode != 2) {
                    acc[mt][nt] = __builtin_amdgcn_mfma_f32_16x16x32_bf16(fah[mt], fbl[nt], acc[mt][nt], 0, 0, 0);
                    acc[mt][nt] = __builtin_amdgcn_mfma_f32_16x16x32_bf16(fal[mt], fbh[nt], acc[mt][nt], 0, 0, 0);
                }
            }
    }

    // ---- fused row norms (modes 0/1; wave's wn-half spans one head) ----
    if (mode == 0 || mode == 1) {
        float* Np = (mode == 0) ? QN : KN;
        const int head = (n0 + wn * 64) >> 6;
        #pragma unroll
        for (int mt = 0; mt < 2; ++mt)
            #pragma unroll
            for (int r = 0; r < 4; ++r) {
                float s = 0.f;
                #pragma unroll
                for (int nt = 0; nt < 4; ++nt) s = fmaf(acc[mt][nt][r], acc[mt][nt][r], s);
                s += __shfl_xor(s, 1);
                s += __shfl_xor(s, 2);
                s += __shfl_xor(s, 4);
                s += __shfl_xor(s, 8);
                if (lx == 0) {
                    const int m = m0 + wm * 32 + mt * 16 + q4 * 4 + r;
                    Np[(size_t)((m >> 11) * HH + head) * NN + (m & 2047)] = s;
                }
            }
    }

    // ---- epilogue (C row m = q4*4+reg, col j = lx) ----
    if (mode == 2) {
        #pragma unroll
        for (int mt = 0; mt < 2; ++mt) {
            const int mb = m0 + wm * 32 + mt * 16 + q4 * 4;
            const int b = mb >> 11, nb = mb & 2047;
            #pragma unroll
            for (int nt = 0; nt < 4; ++nt) {
                const int j = n0 + wn * 64 + nt * 16 + lx;
                ushort4 pv = pk4(acc[mt][nt][0], acc[mt][nt][1],
                                 acc[mt][nt][2], acc[mt][nt][3]);
                *(ushort4*)(Vt + ((size_t)(b * HH + (j >> 6)) * 64 + (j & 63)) * NN + nb) = pv;
            }
        }
    } else {
        #pragma unroll
        for (int mt = 0; mt < 2; ++mt) {
            #pragma unroll
            for (int r = 0; r < 4; ++r) {
                const int m = m0 + wm * 32 + mt * 16 + q4 * 4 + r;
                const int b = m >> 11, n2 = m & 2047;
                #pragma unroll
                for (int nt = 0; nt < 4; ++nt) {
                    const int j = n0 + wn * 64 + nt * 16 + lx;
                    const float v = acc[mt][nt][r];
                    const size_t idx = (((size_t)(b * HH + (j >> 6)) * NN + n2) << 6) + (j & 63);
                    const unsigned short h = f2bf(v);
                    const unsigned short l = f2bf(v - bf2f(h));
                    if (mode == 0) { Qhi[idx] = h; Qlo[idx] = l; }
                    else           { Khi[idx] = h; Klo[idx] = l; }
                }
            }
        }
    }
}

// ---------------------------------------------------------------------------
// Output projection, plain bf16: out = AO @ Wo^T. B = pre-split Wo bf16.
// ---------------------------------------------------------------------------
__global__ __launch_bounds__(256, 4)
void mm_out(const unsigned short* __restrict__ AO, const unsigned short* __restrict__ Wob,
            float* __restrict__ Outp)
{
    const int m0 = blockIdx.x * 64, n0 = blockIdx.y * 64;

    __shared__ unsigned short Ah_s[4 * 64 * 8];    // [kq][64][8]
    __shared__ unsigned short Bh_s[4 * 64 * 8];

    const int tid  = threadIdx.x;
    const int lane = tid & 63, lx = lane & 15, q4 = lane >> 4;
    const int w = tid >> 6, wm = w & 1, wn = w >> 1;
    const int rowA = tid & 63, kqA = tid >> 6;

    f32x4 acc[2][2];
    #pragma unroll
    for (int mt = 0; mt < 2; ++mt)
        #pragma unroll
        for (int nt = 0; nt < 2; ++nt)
            acc[mt][nt] = (f32x4){0.f, 0.f, 0.f, 0.f};

    const int am = m0 + rowA;
    const int ab = am >> 11, an = am & 2047;
    const size_t brow = (size_t)(n0 + rowA) * DDIM;

    uint4 rah, rbh;
    {
        const int e = kqA * 8;
        rah = *(const uint4*)(AO + (((size_t)(ab * HH + (e >> 6)) * NN + an) << 6) + (e & 63));
        rbh = *(const uint4*)(Wob + brow + e);
    }

    for (int k0 = 0; k0 < DDIM; k0 += 32) {
        __syncthreads();
        {
            const int off = (kqA << 9) + (rowA << 3);
            *(uint4*)&Ah_s[off] = rah;
            *(uint4*)&Bh_s[off] = rbh;
        }
        __syncthreads();

        if (k0 + 32 < DDIM) {
            const int e = k0 + 32 + kqA * 8;
            rah = *(const uint4*)(AO + (((size_t)(ab * HH + (e >> 6)) * NN + an) << 6) + (e & 63));
            rbh = *(const uint4*)(Wob + brow + e);
        }

        bf16x8 fah[2], fbh[2];
        #pragma unroll
        for (int mt = 0; mt < 2; ++mt)
            fah[mt] = *(const bf16x8*)&Ah_s[(q4 << 9) + ((wm * 32 + mt * 16 + lx) << 3)];
        #pragma unroll
        for (int nt = 0; nt < 2; ++nt)
            fbh[nt] = *(const bf16x8*)&Bh_s[(q4 << 9) + ((wn * 32 + nt * 16 + lx) << 3)];
        #pragma unroll
        for (int mt = 0; mt < 2; ++mt)
            #pragma unroll
            for (int nt = 0; nt < 2; ++nt)
                acc[mt][nt] = __builtin_amdgcn_mfma_f32_16x16x32_bf16(fah[mt], fbh[nt], acc[mt][nt], 0, 0, 0);
    }

    #pragma unroll
    for (int mt = 0; mt < 2; ++mt)
        #pragma unroll
        for (int r = 0; r < 4; ++r) {
            const int m = m0 + wm * 32 + mt * 16 + q4 * 4 + r;
            #pragma unroll
            for (int nt = 0; nt < 2; ++nt)
                Outp[(size_t)m * DDIM + n0 + wn * 32 + nt * 16 + lx] = acc[mt][nt][r];
        }
}

// ---------------------------------------------------------------------------
// MFMA flash attention, split-K, S^T formulation (round 10). Round-11:
// packed bf16 converts (v_cvt_pk_bf16_f32) for P and epilogue; Opart in bf16
// (halves partial HBM round-trip; error ~0.4% relative, P is bf16 anyway).
// ---------------------------------------------------------------------------
__global__ __launch_bounds__(256, 4)
void attn_mfma(const unsigned short* __restrict__ Qhi, const unsigned short* __restrict__ Qlo,
               const unsigned short* __restrict__ Khi, const unsigned short* __restrict__ Klo,
               const unsigned short* __restrict__ Vt,
               const float* __restrict__ QN, const float* __restrict__ KN,
               const float* __restrict__ pLC, const float* __restrict__ pLB,
               unsigned short* __restrict__ Opart, float* __restrict__ Mp, float* __restrict__ Lp)
{
    __shared__ unsigned short Kh_s[8 * 64 * 8];   // [dchunk][key][8]
    __shared__ unsigned short Kl_s[8 * 64 * 8];
    __shared__ unsigned short Vt_s[8 * 64 * 8];   // [keychunk][d][8]
    __shared__ unsigned short P_s [8 * 64 * 8];   // [keychunk][qrow][8]
    __shared__ __align__(16) float kn_s[64];
    __shared__ float qn_s[64];

    // decode (qt, chunk): group g = qt>>2 has C=g+1 chunks/qt, base 2g(g+1)
    const int idx = blockIdx.x;
    const int g   = (idx >= 112) ? 7 : (idx >= 84) ? 6 : (idx >= 60) ? 5 :
                    (idx >= 40) ? 4 : (idx >= 24) ? 3 : (idx >= 12) ? 2 :
                    (idx >= 4)  ? 1 : 0;
    const int rem = idx - 2 * g * (g + 1);
    const int C   = g + 1;
    const int qt  = g * 4 + rem / C;
    const int c0  = rem % C;
    const int bh  = blockIdx.y;
    const int nk  = qt + 1;
    const int kt0  = (c0 * nk) / C;        // balanced ranges (len 2..4)
    const int kend = ((c0 + 1) * nk) / C;

    const int tid  = threadIdx.x;
    const int w    = tid >> 6;
    const int lane = tid & 63;
    const int lx   = lane & 15;
    const int q4   = lane >> 4;
    const int qrl  = w * 16 + lx;          // this thread's (single) local q-row

    const float hc    = softplus_f(pLC[0]);
    const float betaL = (softplus_f(pLB[0]) + 0.5f) * 1.44269504f;  // log2 domain

    const size_t base = ((size_t)bh * NN) << 6;

    // Q fragments (lane holds row qt*64+qrl, k-chunk q4*8) — serve as B operand
    const unsigned short* qrh = Qhi + base + ((size_t)(qt * 64 + qrl) << 6) + q4 * 8;
    const unsigned short* qrl_p = Qlo + base + ((size_t)(qt * 64 + qrl) << 6) + q4 * 8;
    const bf16x8 qh0 = *(const bf16x8*)(qrh);
    const bf16x8 qh1 = *(const bf16x8*)(qrh + 32);
    const bf16x8 ql0 = *(const bf16x8*)(qrl_p);
    const bf16x8 ql1 = *(const bf16x8*)(qrl_p + 32);

    if (tid < 64) qn_s[tid] = QN[(size_t)bh * NN + qt * 64 + tid];

    f32x4 Oacc[4];     // O^T: d = t2*16+q4*4+r, qrow = qrl
    #pragma unroll
    for (int t = 0; t < 4; ++t) Oacc[t] = (f32x4){0.f, 0.f, 0.f, 0.f};
    float m_st = -INFINITY, l_st = 0.f;

    const int sc = tid >> 6, sr = tid & 63;

    // prefetch first tile (kt0)
    uint4 pKh0, pKh1, pKl0, pKl1, pVt0, pVt1; float pkn = 0.f;
    {
        const unsigned short* kh = Khi + base + ((size_t)(kt0 * 64 + sr) << 6) + sc * 8;
        const unsigned short* kl = Klo + base + ((size_t)(kt0 * 64 + sr) << 6) + sc * 8;
        const unsigned short* vt = Vt  + base + (size_t)sr * NN + kt0 * 64 + sc * 8;
        pKh0 = *(const uint4*)(kh);  pKh1 = *(const uint4*)(kh + 32);
        pKl0 = *(const uint4*)(kl);  pKl1 = *(const uint4*)(kl + 32);
        pVt0 = *(const uint4*)(vt);  pVt1 = *(const uint4*)(vt + 32);
        if (tid < 64) pkn = KN[(size_t)bh * NN + kt0 * 64 + tid];
    }

    __syncthreads();   // qn_s visible
    const float qn = qn_s[qrl];

    for (int kt = kt0; kt < kend; ++kt) {
        // ---- commit prefetched tile (lane-contiguous, conflict-free) ----
        const int soff = (sc << 9) + (sr << 3);
        *(uint4*)&Kh_s[soff]            = pKh0;
        *(uint4*)&Kh_s[soff + (4 << 9)] = pKh1;
        *(uint4*)&Kl_s[soff]            = pKl0;
        *(uint4*)&Kl_s[soff + (4 << 9)] = pKl1;
        *(uint4*)&Vt_s[soff]            = pVt0;
        *(uint4*)&Vt_s[soff + (4 << 9)] = pVt1;
        if (tid < 64) kn_s[tid] = pkn;
        __syncthreads();

        // ---- prefetch tile kt+1 ----
        if (kt + 1 < kend) {
            const unsigned short* kh = Khi + base + ((size_t)((kt + 1) * 64 + sr) << 6) + sc * 8;
            const unsigned short* kl = Klo + base + ((size_t)((kt + 1) * 64 + sr) << 6) + sc * 8;
            const unsigned short* vt = Vt  + base + (size_t)sr * NN + (kt + 1) * 64 + sc * 8;
            pKh0 = *(const uint4*)(kh);  pKh1 = *(const uint4*)(kh + 32);
            pKl0 = *(const uint4*)(kl);  pKl1 = *(const uint4*)(kl + 32);
            pVt0 = *(const uint4*)(vt);  pVt1 = *(const uint4*)(vt + 32);
            if (tid < 64) pkn = KN[(size_t)bh * NN + (kt + 1) * 64 + tid];
        }

        // ---- S^T = K Q^T (hi/lo compensated): A = K rows, B = Q rows ----
        f32x4 S[4];    // S[t][r]: key = t*16 + q4*4 + r, qrow = qrl
        #pragma unroll
        for (int t = 0; t < 4; ++t) {
            f32x4 acc = (f32x4){0.f, 0.f, 0.f, 0.f};
            #pragma unroll
            for (int c2 = 0; c2 < 2; ++c2) {
                const int off = ((c2 * 4 + q4) << 9) + ((t * 16 + lx) << 3);
                const bf16x8 kh = *(const bf16x8*)&Kh_s[off];
                const bf16x8 kl = *(const bf16x8*)&Kl_s[off];
                const bf16x8 qh = c2 ? qh1 : qh0;
                const bf16x8 ql = c2 ? ql1 : ql0;
                acc = __builtin_amdgcn_mfma_f32_16x16x32_bf16(kh, qh, acc, 0, 0, 0);
                acc = __builtin_amdgcn_mfma_f32_16x16x32_bf16(kh, ql, acc, 0, 0, 0);
                acc = __builtin_amdgcn_mfma_f32_16x16x32_bf16(kl, qh, acc, 0, 0, 0);
            }
            S[t] = acc;
        }

        // ---- hyperbolic distance -> log2-scores (all 16 share qrow qrl) ----
        const bool diag = (kt == qt);
        float mloc = -INFINITY;
        #pragma unroll
        for (int t = 0; t < 4; ++t) {
            float kn4[4];
            *(float4*)kn4 = *(const float4*)&kn_s[t * 16 + q4 * 4];
            #pragma unroll
            for (int r = 0; r < 4; ++r) {
                const float sumn = qn + kn4[r];
                float diff = fmaxf(fmaf(-2.f, S[t][r], sumn), 0.f);
                float s = -betaL * sqrtf(fmaf(hc, sumn, 1.f) * (diff + 1e-8f));
                if (diag && (t * 16 + q4 * 4 + r) > qrl) s = -INFINITY;
                S[t][r] = s;
                mloc = fmaxf(mloc, s);
            }
        }
        mloc = fmaxf(mloc, __shfl_xor(mloc, 16));
        mloc = fmaxf(mloc, __shfl_xor(mloc, 32));
        const float mn = fmaxf(m_st, mloc);
        const float al = exp2f(m_st - mn);
        m_st = mn;

        float rs = 0.f;
        #pragma unroll
        for (int t = 0; t < 4; ++t) {
            const float p0 = exp2f(S[t][0] - mn);
            const float p1 = exp2f(S[t][1] - mn);
            const float p2 = exp2f(S[t][2] - mn);
            const float p3 = exp2f(S[t][3] - mn);
            rs += (p0 + p1) + (p2 + p3);
            // keys t*16+q4*4+{0..3} are LDS-consecutive -> one b64 store
            *(ushort4*)&P_s[((2 * t + (q4 >> 1)) << 9) + (qrl << 3) + ((q4 & 1) << 2)] =
                pk4(p0, p1, p2, p3);
        }
        rs += __shfl_xor(rs, 16);
        rs += __shfl_xor(rs, 32);
        l_st = l_st * al + rs;
        #pragma unroll
        for (int t = 0; t < 4; ++t) {
            Oacc[t][0] *= al; Oacc[t][1] *= al;
            Oacc[t][2] *= al; Oacc[t][3] *= al;
        }

        // P_s rows qrl are wave-local; same-wave DS ops pipe-ordered.
        __builtin_amdgcn_wave_barrier();

        // ---- O^T += V^T P : A = Vt rows (d), B = P (qrow cols) ----
        #pragma unroll
        for (int c2 = 0; c2 < 2; ++c2) {
            const bf16x8 pb = *(const bf16x8*)&P_s[((c2 * 4 + q4) << 9) + (qrl << 3)];
            #pragma unroll
            for (int t2 = 0; t2 < 4; ++t2) {
                const bf16x8 va = *(const bf16x8*)&Vt_s[((c2 * 4 + q4) << 9) + ((t2 * 16 + lx) << 3)];
                Oacc[t2] = __builtin_amdgcn_mfma_f32_16x16x32_bf16(va, pb, Oacc[t2], 0, 0, 0);
            }
        }
        __syncthreads();   // all waves done reading K/Vt/P before next commit
    }

    // ---- epilogue: partial [qrow][d] bf16 + (m2, l); slot = per-bh idx ----
    const int slot = bh * CPB + idx;
    unsigned short* op = Opart + ((size_t)slot << 12);
    #pragma unroll
    for (int t2 = 0; t2 < 4; ++t2)
        *(ushort4*)&op[qrl * 64 + t2 * 16 + q4 * 4] =
            pk4(Oacc[t2][0], Oacc[t2][1], Oacc[t2][2], Oacc[t2][3]);
    if (q4 == 0) {
        Mp[slot * 64 + qrl] = m_st;   // log2 domain
        Lp[slot * 64 + qrl] = l_st;
    }
}

// ---------------------------------------------------------------------------
// Combine <=8 chunk partials per (bh, qt), log2-domain weights; AO bf16.
// Opart now bf16 (half the read traffic of round 10).
// ---------------------------------------------------------------------------
__global__ __launch_bounds__(256)
void attn_combine(const unsigned short* __restrict__ Opart, const float* __restrict__ Mp,
                  const float* __restrict__ Lp, unsigned short* __restrict__ AO)
{
    const int bh = blockIdx.x >> 5, qt = blockIdx.x & 31;
    const int g = qt >> 2, C = g + 1;
    const int first = 2 * g * (g + 1) + (qt & 3) * C;
    const int row = threadIdx.x >> 2, qd = threadIdx.x & 3;
    const int slot0 = bh * CPB + first;

    float m = -INFINITY;
    for (int c = 0; c < C; ++c) m = fmaxf(m, Mp[(slot0 + c) * 64 + row]);
    float L = 0.f;
    float o[16];
    #pragma unroll
    for (int j = 0; j < 16; ++j) o[j] = 0.f;

    for (int c = 0; c < C; ++c) {
        const float wgt = exp2f(Mp[(slot0 + c) * 64 + row] - m);
        L += wgt * Lp[(slot0 + c) * 64 + row];
        const unsigned short* op = Opart + (((size_t)(slot0 + c)) << 12) + row * 64 + qd * 16;
        union { uint4 v; unsigned short u[8]; } a0, a1;
        a0.v = *(const uint4*)(op);
        a1.v = *(const uint4*)(op + 8);
        #pragma unroll
        for (int j = 0; j < 8; ++j) {
            o[j]     = fmaf(wgt, bf2f(a0.u[j]), o[j]);
            o[j + 8] = fmaf(wgt, bf2f(a1.u[j]), o[j + 8]);
        }
    }

    const float inv = 1.f / L;
    const size_t obase = (((size_t)bh * NN + qt * 64 + row) << 6) + qd * 16;
    *(ushort4*)(AO + obase)      = pk4(o[0]*inv,  o[1]*inv,  o[2]*inv,  o[3]*inv);
    *(ushort4*)(AO + obase + 4)  = pk4(o[4]*inv,  o[5]*inv,  o[6]*inv,  o[7]*inv);
    *(ushort4*)(AO + obase + 8)  = pk4(o[8]*inv,  o[9]*inv,  o[10]*inv, o[11]*inv);
    *(ushort4*)(AO + obase + 12) = pk4(o[12]*inv, o[13]*inv, o[14]*inv, o[15]*inv);
}

// ---------------------------------------------------------------------------
extern "C" void kernel_launch(void* const* d_in, const int* in_sizes, int n_in,
                              void* d_out, int out_size, void* d_ws, size_t ws_size,
                              hipStream_t stream)
{
    const float* x        = (const float*)d_in[0];
    const float* Wq       = (const float*)d_in[1];
    const float* Wk       = (const float*)d_in[2];
    const float* Wv       = (const float*)d_in[3];
    const float* Wo       = (const float*)d_in[4];
    const float* log_c    = (const float*)d_in[5];
    const float* log_beta = (const float*)d_in[6];
    float* out = (float*)d_out;

    unsigned short* p = (unsigned short*)d_ws;
    unsigned short* Qhi = p;            p += EE;
    unsigned short* Qlo = p;            p += EE;
    unsigned short* Khi = p;            p += EE;
    unsigned short* Klo = p;            p += EE;
    unsigned short* Vtr = p;            p += EE;
    unsigned short* AO  = p;            p += EE;
    unsigned short* Whi = p;            p += 3 * (size_t)WN;
    unsigned short* Wlo = p;            p += 3 * (size_t)WN;
    unsigned short* Wob = p;            p += WN;
    unsigned short* Opart = p;          p += (size_t)NSLOT * 4096;
    float* QN = (float*)p;
    float* KN = QN + (size_t)BB * HH * NN;
    float* Mp = KN + (size_t)BB * HH * NN;
    float* Lp = Mp + (size_t)NSLOT * 64;

    split_w<<<dim3(WN / 1024, 4), 256, 0, stream>>>(Wq, Wk, Wv, Wo, Whi, Wlo, Wob);
    mm_proj<<<dim3(MTOT / 64, DDIM / 128, 3), 256, 0, stream>>>(
        x, Whi, Wlo, Qhi, Qlo, Khi, Klo, Vtr, QN, KN);
    attn_mfma<<<dim3(CPB, 16), 256, 0, stream>>>(Qhi, Qlo, Khi, Klo, Vtr, QN, KN,
                                                 log_c, log_beta, Opart, Mp, Lp);
    attn_combine<<<dim3(512), 256, 0, stream>>>(Opart, Mp, Lp, AO);
    mm_out<<<dim3(MTOT / 64, DDIM / 64), 256, 0, stream>>>(AO, Wob, out);
}